// Round 9
// baseline (271.985 us; speedup 1.0000x reference)
//
#include <hip/hip_runtime.h>
#include <math.h>

// Problem constants: B=2, T=2048, D=768, H=12, HS=64, FF=3072, HALF=1536
#define TDIM 2048
#define DDIM 768
#define NH   12
#define NROWS 4096            // B*T
#define EPSV 1e-8f
#define SCALE 0.03608439182435161f   // 768^-0.5  (ref scales by D, not HS)

typedef __bf16 bf16_t;
typedef bf16_t bf16x8 __attribute__((ext_vector_type(8)));
typedef bf16_t bf16x4 __attribute__((ext_vector_type(4)));
typedef bf16_t bf16x2 __attribute__((ext_vector_type(2)));
typedef float  floatx4 __attribute__((ext_vector_type(4)));
typedef float  f32x16 __attribute__((ext_vector_type(16)));

// async global->LDS, 16B per lane; LDS dest = wave-uniform base + lane*16
__device__ __forceinline__ void glds16(const bf16_t* g, bf16_t* l) {
    __builtin_amdgcn_global_load_lds(
        (const __attribute__((address_space(1))) void*)g,
        (__attribute__((address_space(3))) void*)l, 16, 0, 0);
}

// ------- fused: weight repack (blocks 0..1439) + RMSNorm #1 (1440..5535) -----
__global__ __launch_bounds__(256) void pack_rms(
    const float* __restrict__ Wq, const float* __restrict__ Wk,
    const float* __restrict__ Wv, const float* __restrict__ Wo,
    const float* __restrict__ W1, const float* __restrict__ W2,
    bf16_t* __restrict__ qkvw, bf16_t* __restrict__ wo,
    bf16_t* __restrict__ w1, bf16_t* __restrict__ w2,
    const float* __restrict__ x, const float* __restrict__ g1,
    bf16_t* __restrict__ hout)
{
    __shared__ float Ts[64][65];
    __shared__ float red[4];
    __shared__ float tot;
    int bid = blockIdx.x;
    int tid = threadIdx.x;

    if (bid >= 1440) {                     // ---- RMSNorm path ----
        int row = bid - 1440;
        const float* xr = x + (size_t)row * DDIM;
        float v0 = xr[tid], v1 = xr[tid + 256], v2 = xr[tid + 512];
        float s = v0*v0 + v1*v1 + v2*v2;
        #pragma unroll
        for (int off = 32; off > 0; off >>= 1)
            s += __shfl_down(s, off, 64);
        if ((tid & 63) == 0) red[tid >> 6] = s;
        __syncthreads();
        if (tid == 0) tot = red[0] + red[1] + red[2] + red[3];
        __syncthreads();
        float rms = sqrtf(tot * (1.0f / DDIM));
        float inv = 1.0f / (rms + EPSV);
        bf16_t* orow = hout + (size_t)row * DDIM;
        orow[tid]       = (bf16_t)(g1[tid]       * v0 * inv);
        orow[tid + 256] = (bf16_t)(g1[tid + 256] * v1 * inv);
        orow[tid + 512] = (bf16_t)(g1[tid + 512] * v2 * inv);
        return;
    }

    // ---- pack path ----
    const float* src; bf16_t* dst;
    int srcld, dstld, k0, n0;
    int remap = 0;
    if (bid < 144) {                       // Wo: K=768, N=768 (12x12)
        int kx = bid % 12, nx = bid / 12;
        src = Wo; dst = wo; srcld = 768; dstld = 768; k0 = kx * 64; n0 = nx * 64;
    } else if (bid < 720) {                // W1: K=768, N=3072 (12x48)
        int t = bid - 144; int kx = t % 12, nx = t / 12;
        src = W1; dst = w1; srcld = 3072; dstld = 768; k0 = kx * 64; n0 = nx * 64;
        remap = 1;                         // interleave a/gate columns
    } else if (bid < 1008) {               // W2: K=1536, N=768 (24x12)
        int t = bid - 720; int kx = t % 24, nx = t / 24;
        src = W2; dst = w2; srcld = 768; dstld = 1536; k0 = kx * 64; n0 = nx * 64;
    } else {                               // QKV: 36 mats (768x64), 12 k-tiles
        int t = bid - 1008; int kx = t % 12, y = t / 12;
        int sel = y / 12, h = y - sel * 12;
        src = ((sel == 0) ? Wq : (sel == 1) ? Wk : Wv) + (size_t)h * 768 * 64;
        dst = qkvw + (size_t)(sel * 768 + h * 64) * 768;
        srcld = 64; dstld = 768; k0 = kx * 64; n0 = 0;
    }
    int r = tid >> 2, c = (tid & 3) * 16;
    const float* s = src + (size_t)(k0 + r) * srcld + n0 + c;
    #pragma unroll
    for (int i = 0; i < 4; i++) {
        float4 t = *(const float4*)(s + i * 4);
        Ts[r][c + i*4 + 0] = t.x; Ts[r][c + i*4 + 1] = t.y;
        Ts[r][c + i*4 + 2] = t.z; Ts[r][c + i*4 + 3] = t.w;
    }
    __syncthreads();
    int n = tid >> 2, kk = (tid & 3) * 16;
    bf16x8 o0, o1;
    #pragma unroll
    for (int i = 0; i < 8; i++) {
        o0[i] = (bf16_t)Ts[kk + i][n];
        o1[i] = (bf16_t)Ts[kk + 8 + i][n];
    }
    int oc = n0 + n;
    if (remap) oc = (oc < 1536) ? (oc * 2) : ((oc - 1536) * 2 + 1);
    bf16_t* d = dst + (size_t)oc * dstld + k0 + kk;
    *(bf16x8*)d = o0;
    *(bf16x8*)(d + 8) = o1;
}

// ---------------- RMSNorm -> bf16 (second norm) ----------------
__global__ __launch_bounds__(256) void rmsnorm_bf(
    const float* __restrict__ x, const float* __restrict__ g,
    bf16_t* __restrict__ out)
{
    int row = blockIdx.x;
    int tid = threadIdx.x;
    const float* xr = x + (size_t)row * DDIM;
    float v0 = xr[tid], v1 = xr[tid + 256], v2 = xr[tid + 512];
    float s = v0*v0 + v1*v1 + v2*v2;
    #pragma unroll
    for (int off = 32; off > 0; off >>= 1)
        s += __shfl_down(s, off, 64);
    __shared__ float red[4];
    __shared__ float tot;
    if ((tid & 63) == 0) red[tid >> 6] = s;
    __syncthreads();
    if (tid == 0) tot = red[0] + red[1] + red[2] + red[3];
    __syncthreads();
    float rms = sqrtf(tot * (1.0f / DDIM));
    float inv = 1.0f / (rms + EPSV);
    bf16_t* orow = out + (size_t)row * DDIM;
    orow[tid]       = (bf16_t)(g[tid]       * v0 * inv);
    orow[tid + 256] = (bf16_t)(g[tid + 256] * v1 * inv);
    orow[tid + 512] = (bf16_t)(g[tid + 512] * v2 * inv);
}

// ---------------- bf16 MFMA GEMM, BK=64 twin-buffer, C^T epilogue ------------
// R6-exact (measured best) — do not reintroduce explicit pipelining (R7: -30%).
template<int TM, int EPI>
__global__ __launch_bounds__(256) void gemm_bf16(
    const bf16_t* __restrict__ A, const bf16_t* __restrict__ BT, int K,
    float* __restrict__ Cf, bf16_t* __restrict__ Cb, int ldc,
    const float* __restrict__ bias, const float* __restrict__ resid, int gx)
{
    constexpr int MT = TM / 32;           // m-frags per wave (4 or 2)
    __shared__ bf16_t As0[TM][32], As1[TM][32];      // 64B rows (m97 layout)
    __shared__ bf16_t Bs0[128][32], Bs1[128][32];
    int tid = threadIdx.x;
    int wave = tid >> 6, lane = tid & 63;
    int lrow = lane & 15, quad = lane >> 4;
    int wm = wave >> 1, wn = wave & 1;

    // XCD swizzle: nwg % 8 == 0 for all launches
    int flat = blockIdx.x;
    int cpx = gridDim.x >> 3;
    int swz = (flat & 7) * cpx + (flat >> 3);
    int m0 = (swz / gx) * TM;
    int n0 = (swz % gx) * 128;

    int srow = lane >> 2, scol = (lane & 3) * 8;     // 16 rows x 8 elems per glds
    const bf16_t* Ag = A  + ((size_t)m0 + wave * (TM/4) + srow) * K + scol;
    const bf16_t* Bg = BT + ((size_t)n0 + wave * 32 + srow) * K + scol;

    floatx4 acc[MT][4];
    #pragma unroll
    for (int mt = 0; mt < MT; mt++)
        #pragma unroll
        for (int nt = 0; nt < 4; nt++)
            #pragma unroll
            for (int r = 0; r < 4; r++) acc[mt][nt][r] = 0.f;

    for (int k0 = 0; k0 < K; k0 += 64) {
        __syncthreads();
        #pragma unroll
        for (int i = 0; i < TM/64; i++) {            // 2 (TM=128) or 1 (TM=64)
            glds16(Ag + (size_t)(i*16) * K + k0,      &As0[wave*(TM/4) + i*16][0]);
            glds16(Ag + (size_t)(i*16) * K + k0 + 32, &As1[wave*(TM/4) + i*16][0]);
        }
        #pragma unroll
        for (int i = 0; i < 2; i++) {
            glds16(Bg + (size_t)(i*16) * K + k0,      &Bs0[wave*32 + i*16][0]);
            glds16(Bg + (size_t)(i*16) * K + k0 + 32, &Bs1[wave*32 + i*16][0]);
        }
        __syncthreads();

        bf16x8 af0[MT], af1[MT], bf0[4], bf1[4];
        #pragma unroll
        for (int mt = 0; mt < MT; mt++) {
            af0[mt] = *(const bf16x8*)&As0[wm*(TM/2) + mt*16 + lrow][quad * 8];
            af1[mt] = *(const bf16x8*)&As1[wm*(TM/2) + mt*16 + lrow][quad * 8];
        }
        #pragma unroll
        for (int nt = 0; nt < 4; nt++) {
            bf0[nt] = *(const bf16x8*)&Bs0[wn*64 + nt*16 + lrow][quad * 8];
            bf1[nt] = *(const bf16x8*)&Bs1[wn*64 + nt*16 + lrow][quad * 8];
        }
        #pragma unroll
        for (int mt = 0; mt < MT; mt++)
            #pragma unroll
            for (int nt = 0; nt < 4; nt++) {
                acc[mt][nt] = __builtin_amdgcn_mfma_f32_16x16x32_bf16(
                    bf0[nt], af0[mt], acc[mt][nt], 0, 0, 0);
                acc[mt][nt] = __builtin_amdgcn_mfma_f32_16x16x32_bf16(
                    bf1[nt], af1[mt], acc[mt][nt], 0, 0, 0);
            }
    }

    int crow0 = m0 + wm * (TM/2);
    int ccol0 = n0 + wn * 64;
    #pragma unroll
    for (int mt = 0; mt < MT; mt++) {
        int row = crow0 + mt * 16 + lrow;
        #pragma unroll
        for (int nt = 0; nt < 4; nt++) {
            int col = ccol0 + nt * 16 + quad * 4;
            floatx4 a = acc[mt][nt];
            if constexpr (EPI == 1) {
                int c = col >> 1;
                float2 ba = *(const float2*)(bias + c);
                float2 bg = *(const float2*)(bias + 1536 + c);
                float a0 = a[0] + ba.x, g0 = a[1] + bg.x;
                float a1 = a[2] + ba.y, g1 = a[3] + bg.y;
                bf16x2 v;
                v[0] = (bf16_t)(a0 * (g0 / (1.0f + __expf(-g0))));
                v[1] = (bf16_t)(a1 * (g1 / (1.0f + __expf(-g1))));
                *(bf16x2*)(Cb + (size_t)row * ldc + c) = v;
            } else {
                size_t off = (size_t)row * ldc + col;
                float4 bv = make_float4(0.f, 0.f, 0.f, 0.f);
                if (bias) bv = *(const float4*)(bias + col);
                float4 rs = make_float4(0.f, 0.f, 0.f, 0.f);
                if (resid) rs = *(const float4*)(resid + off);
                if (Cf) {
                    float4 v;
                    v.x = a[0] + bv.x + rs.x; v.y = a[1] + bv.y + rs.y;
                    v.z = a[2] + bv.z + rs.z; v.w = a[3] + bv.w + rs.w;
                    *(float4*)(Cf + off) = v;
                } else {
                    bf16x4 v;
                    v[0] = (bf16_t)(a[0] + bv.x + rs.x);
                    v[1] = (bf16_t)(a[1] + bv.y + rs.y);
                    v[2] = (bf16_t)(a[2] + bv.z + rs.z);
                    v[3] = (bf16_t)(a[3] + bv.w + rs.w);
                    *(bf16x4*)(Cb + off) = v;
                }
            }
        }
    }
}

// ---------------- V transpose: qkv V-part -> vt[bh][dim][t] ----------------
__global__ __launch_bounds__(256) void vt_kernel(
    const bf16_t* __restrict__ qkv, bf16_t* __restrict__ vt)
{
    __shared__ bf16_t Ts[64][72];
    int t0 = blockIdx.x * 64;
    int bh = blockIdx.y;
    int b = bh / NH, h = bh - b * NH;
    int tid = threadIdx.x;
    int r = tid >> 2, c = (tid & 3) * 16;
    const bf16_t* src = qkv + ((size_t)b * TDIM + t0 + r) * 2304 + 1536 + h * 64 + c;
    *(bf16x8*)&Ts[r][c]     = *(const bf16x8*)src;
    *(bf16x8*)&Ts[r][c + 8] = *(const bf16x8*)(src + 8);
    __syncthreads();
    int d = tid >> 2, tt = (tid & 3) * 16;
    bf16x8 o0, o1;
    #pragma unroll
    for (int i = 0; i < 8; i++) {
        o0[i] = Ts[tt + i][d];
        o1[i] = Ts[tt + 8 + i][d];
    }
    bf16_t* dst = vt + ((size_t)bh * 64 + d) * TDIM + t0 + tt;
    *(bf16x8*)dst = o0;
    *(bf16x8*)(dst + 8) = o1;
}

// ---------------- MFMA flash attention v6: 32x32 MFMA, in-reg P -------------
// LDS-pipe analysis (R8): v3 issued ~192 LDS cycles/wave-iter x 12 waves >
// iter period -> LDS pipe saturated (explains idle MFMA/VALU + null latency
// fixes R3-R5). v6 cuts LDS bytes/work ~4.6x:
//  - 32x32x16 MFMA: 2x FLOP per LDS byte; wave computes 32 q-rows.
//  - P stays in registers: S^T C-layout puts a q-column's P in lanes {l,l^32};
//    PV B-frag built with 4 shfl_xor(32) + cndmask per k-slice. No Ps LDS.
//  - 128 q-rows/block (2 q-tiles share one K/V stream): staging + global K/V
//    per q-row halves; iters/bh 528->272. Grid 384.
// Layouts (m74/m101/m89): A row=lane&31,k=(lane>>5)*8+j; B col=lane&31,same k;
// C/D col=lane&31, row=(reg&3)+8*(reg>>2)+4*(lane>>5).
__global__ __launch_bounds__(256) void attn_mfma(
    const bf16_t* __restrict__ qkv, const bf16_t* __restrict__ vt,
    bf16_t* __restrict__ o)
{
    const int QS = 2304;
    int bid = blockIdx.x;
    // schedule: CUs pair long t with short t (blocks run concurrently -> CU
    // time ~ longest chain); singles get mid t. bids == mod 256 share a CU.
    int idx;
    if (bid >= 128 && bid < 256) idx = 168 + (bid - 128);        // singles
    else if (bid < 128)          idx = bid;                       // pair-first
    else { int p = 511 - bid; idx = (p >= 168) ? p + 128 : p; }   // pair-second
    int t = idx / 24, bh = idx % 24;
    int b = bh / NH, h = bh - b * NH;
    int tid = threadIdx.x;
    int wave = tid >> 6, lane = tid & 63;
    int l31 = lane & 31, hi = lane >> 5;

    __shared__ bf16_t Ks[2][64][72];      // K tile: row = kc, col = dim
    __shared__ bf16_t Vts[2][64][72];     // V^T: row = dim, col = kc

    size_t rbase = (size_t)b * TDIM;
    int st = 2 * t + 1;                   // last kv-tile index for this block
    int qtw = st - 1 + (wave >> 1);       // this wave's causal-final tile
    int q0w = t * 128 + wave * 32;        // wave's 32-row q strip

    const bf16_t* qp = qkv + (rbase + q0w + l31) * QS + h * 64;
    bf16x8 qf[4];
    #pragma unroll
    for (int ds = 0; ds < 4; ds++)
        qf[ds] = *(const bf16x8*)(qp + ds * 16 + hi * 8);

    f32x16 o_acc[2];                      // O^T: dim = dt*32+crow, q = l31
    #pragma unroll
    for (int dt = 0; dt < 2; dt++)
        #pragma unroll
        for (int r = 0; r < 16; r++) o_acc[dt][r] = 0.f;
    float m_r = -INFINITY, l_r = 0.f;

    int srow = tid >> 2;                  // 0..63
    int scol = (tid & 3) * 16;            // 0,16,32,48
    const bf16_t* kbase = qkv + (rbase + srow) * QS + 768 + h * 64 + scol;
    const bf16_t* vbase = vt + ((size_t)bh * 64 + srow) * TDIM + scol;

    // prologue: tile 0 -> LDS buf0; prefetch tile 1 into regs (st >= 1 always)
    bf16x8 kr0 = *(const bf16x8*)kbase;
    bf16x8 kr1 = *(const bf16x8*)(kbase + 8);
    bf16x8 vr0 = *(const bf16x8*)vbase;
    bf16x8 vr1 = *(const bf16x8*)(vbase + 8);
    *(bf16x8*)&Ks[0][srow][scol]      = kr0;
    *(bf16x8*)&Ks[0][srow][scol + 8]  = kr1;
    *(bf16x8*)&Vts[0][srow][scol]     = vr0;
    *(bf16x8*)&Vts[0][srow][scol + 8] = vr1;
    {
        const bf16_t* kp = kbase + (size_t)64 * QS;
        const bf16_t* vp = vbase + 64;
        kr0 = *(const bf16x8*)kp;  kr1 = *(const bf16x8*)(kp + 8);
        vr0 = *(const bf16x8*)vp;  vr1 = *(const bf16x8*)(vp + 8);
    }
    asm volatile("s_waitcnt lgkmcnt(0)" ::: "memory");
    __builtin_amdgcn_s_barrier();

    for (int s = 0; s <= st; s++) {
        int cur = s & 1;
        int live = (s <= qtw);            // wave-uniform

        f32x16 sf[2];
        if (live) {
            // S^T = K Q^T: row = kc (kct*32 + crow), col = q (l31)
            #pragma unroll
            for (int kct = 0; kct < 2; kct++) {
                #pragma unroll
                for (int r = 0; r < 16; r++) sf[kct][r] = 0.f;
            }
            __builtin_amdgcn_s_setprio(1);
            #pragma unroll
            for (int kct = 0; kct < 2; kct++)
                #pragma unroll
                for (int ds = 0; ds < 4; ds++) {
                    bf16x8 afr = *(const bf16x8*)&Ks[cur][kct*32 + l31][ds*16 + hi*8];
                    sf[kct] = __builtin_amdgcn_mfma_f32_32x32x16_bf16(
                        afr, qf[ds], sf[kct], 0, 0, 0);
                }
            __builtin_amdgcn_s_setprio(0);
        }

        // write-late: stage tile s+1 (regs loaded an iteration ago); readers
        // of buf nxt only start after the barrier below. All waves participate.
        if (s < st) {
            int nxt = cur ^ 1;
            *(bf16x8*)&Ks[nxt][srow][scol]      = kr0;
            *(bf16x8*)&Ks[nxt][srow][scol + 8]  = kr1;
            *(bf16x8*)&Vts[nxt][srow][scol]     = vr0;
            *(bf16x8*)&Vts[nxt][srow][scol + 8] = vr1;
        }

        if (live) {
            if (s == qtw) {
                int qg = q0w + l31;
                #pragma unroll
                for (int kct = 0; kct < 2; kct++)
                    #pragma unroll
                    for (int r = 0; r < 16; r++) {
                        int kc = s*64 + kct*32 + (r&3) + 8*(r>>2) + 4*hi;
                        sf[kct][r] = (kc > qg) ? -INFINITY : sf[kct][r] * SCALE;
                    }
            } else {
                #pragma unroll
                for (int kct = 0; kct < 2; kct++)
                    #pragma unroll
                    for (int r = 0; r < 16; r++) sf[kct][r] *= SCALE;
            }

            // online softmax: lane holds 32 kc for its q; partner (l^32) has
            // the other 32 -> one shfl_xor(32). Deferred rescale (THR=8).
            float mx = sf[0][0];
            #pragma unroll
            for (int kct = 0; kct < 2; kct++)
                #pragma unroll
                for (int r = 0; r < 16; r++) mx = fmaxf(mx, sf[kct][r]);
            mx = fmaxf(mx, __shfl_xor(mx, 32, 64));
            if (__any(mx > m_r + 8.0f)) {
                float mn = fmaxf(m_r, mx);
                float alpha = __expf(m_r - mn);
                m_r = mn;
                l_r *= alpha;
                #pragma unroll
                for (int dt = 0; dt < 2; dt++)
                    #pragma unroll
                    for (int r = 0; r < 16; r++) o_acc[dt][r] *= alpha;
            }
            float ls = 0.f;
            #pragma unroll
            for (int kct = 0; kct < 2; kct++)
                #pragma unroll
                for (int r = 0; r < 16; r++) {
                    float e = __expf(sf[kct][r] - m_r);
                    ls += e;
                    sf[kct][r] = e;
                }
            ls += __shfl_xor(ls, 32, 64);
            l_r += ls;

            // PV: O^T += V^T P^T. P^T B-frag assembled in-register per kcslice:
            // hi=0 frag = {ownA, recvA}; hi=1 frag = {recvB, ownB}.
            __builtin_amdgcn_s_setprio(1);
            #pragma unroll
            for (int ks = 0; ks < 4; ks++) {
                int kct = ks >> 1, base = (ks & 1) * 8;
                bf16x4 A, Bv;
                #pragma unroll
                for (int j = 0; j < 4; j++) {
                    A[j]  = (bf16_t)sf[kct][base + j];
                    Bv[j] = (bf16_t)sf[kct][base + 4 + j];
                }
                int2 ai = *(int2*)&A, bi = *(int2*)&Bv;
                int2 ra, rb2;
                ra.x  = __shfl_xor(ai.x, 32, 64);
                ra.y  = __shfl_xor(ai.y, 32, 64);
                rb2.x = __shfl_xor(bi.x, 32, 64);
                rb2.y = __shfl_xor(bi.y, 32, 64);
                int4 pd;
                pd.x = hi ? rb2.x : ai.x;
                pd.y = hi ? rb2.y : ai.y;
                pd.z = hi ? bi.x : ra.x;
                pd.w = hi ? bi.y : ra.y;
                bf16x8 pb = *(bf16x8*)&pd;
                #pragma unroll
                for (int dt = 0; dt < 2; dt++) {
                    bf16x8 vfr = *(const bf16x8*)&Vts[cur][dt*32 + l31][ks*16 + hi*8];
                    o_acc[dt] = __builtin_amdgcn_mfma_f32_32x32x16_bf16(
                        vfr, pb, o_acc[dt], 0, 0, 0);
                }
            }
            __builtin_amdgcn_s_setprio(0);
        }

        // issue-early: global loads for tile s+2 (staged at end of iter s+1)
        if (s + 2 <= st) {
            const bf16_t* kp = kbase + (size_t)(s + 2) * 64 * QS;
            const bf16_t* vp = vbase + (size_t)(s + 2) * 64;
            kr0 = *(const bf16x8*)kp;  kr1 = *(const bf16x8*)(kp + 8);
            vr0 = *(const bf16x8*)vp;  vr1 = *(const bf16x8*)(vp + 8);
        }

        // LDS-only fence + raw barrier: keep the global prefetch in flight
        asm volatile("s_waitcnt lgkmcnt(0)" ::: "memory");
        __builtin_amdgcn_s_barrier();
    }

    float inv = 1.0f / l_r;
    size_t rb = (rbase + q0w + l31) * DDIM + h * 64;
    #pragma unroll
    for (int dt = 0; dt < 2; dt++)
        #pragma unroll
        for (int J = 0; J < 4; J++) {
            bf16x4 ov;
            #pragma unroll
            for (int rr = 0; rr < 4; rr++)
                ov[rr] = (bf16_t)(o_acc[dt][4*J + rr] * inv);
            *(bf16x4*)(o + rb + dt*32 + 8*J + 4*hi) = ov;
        }
}

extern "C" void kernel_launch(void* const* d_in, const int* in_sizes, int n_in,
                              void* d_out, int out_size, void* d_ws, size_t ws_size,
                              hipStream_t stream) {
    const float* x  = (const float*)d_in[0];
    const float* Wq = (const float*)d_in[1];
    const float* Wk = (const float*)d_in[2];
    const float* Wv = (const float*)d_in[3];
    const float* Wo = (const float*)d_in[4];
    const float* bo = (const float*)d_in[5];
    const float* W1 = (const float*)d_in[6];
    const float* b1 = (const float*)d_in[7];
    const float* W2 = (const float*)d_in[8];
    const float* b2 = (const float*)d_in[9];
    const float* g1 = (const float*)d_in[10];
    const float* g2 = (const float*)d_in[11];
    float* out = (float*)d_out;
    char* ws = (char*)d_ws;

    bf16_t* qkvw_bt = (bf16_t*)(ws);                    // 2304x768
    bf16_t* wo_bt   = (bf16_t*)(ws + 3538944);          // 768x768
    bf16_t* w1_bt   = (bf16_t*)(ws + 4718592);          // 3072x768 (interleaved)
    bf16_t* w2_bt   = (bf16_t*)(ws + 9437184);          // 768x1536
    bf16_t* h_bf    = (bf16_t*)(ws + 11796480);         // 4096x768
    bf16_t* qkv     = (bf16_t*)(ws + 18087936);         // 4096x2304
    bf16_t* attn_bf = (bf16_t*)(ws + 36962304);         // 4096x768
    bf16_t* sw_bf   = (bf16_t*)(ws + 68419584);         // 4096x1536
    bf16_t* vt      = (bf16_t*)(ws + 81002496);         // 24x64x2048

    // fused: weight pack (1440 blocks) + rmsnorm #1 (4096 blocks)
    pack_rms<<<5536, 256, 0, stream>>>(Wq, Wk, Wv, Wo, W1, W2,
                                       qkvw_bt, wo_bt, w1_bt, w2_bt,
                                       x, g1, h_bf);

    // qkv = h @ [Wq|Wk|Wv]  (4096 x 2304 bf16): 18x32 -> 576 blocks
    gemm_bf16<128, 0><<<576, 256, 0, stream>>>(
        h_bf, qkvw_bt, 768, nullptr, qkv, 2304, nullptr, nullptr, 18);

    vt_kernel<<<dim3(32, 24), 256, 0, stream>>>(qkv, vt);

    attn_mfma<<<384, 256, 0, stream>>>(qkv, vt, attn_bf);

    // out = x + attn @ Wo + bo  (fp32): 6x64 -> 384 blocks
    gemm_bf16<64, 0><<<384, 256, 0, stream>>>(
        attn_bf, wo_bt, 768, out, nullptr, 768, bo, x, 6);

    rmsnorm_bf<<<NROWS, 256, 0, stream>>>(out, g2, h_bf);

    // sw = silu(gate) * a, fused into the W1 GEMM epilogue: 24x32 -> 768 blocks
    gemm_bf16<128, 1><<<768, 256, 0, stream>>>(
        h_bf, w1_bt, 768, nullptr, sw_bf, 1536, b1, nullptr, 24);

    // out = out + sw @ W2 + b2  (fp32): 6x64 -> 384 blocks
    gemm_bf16<64, 0><<<384, 256, 0, stream>>>(
        sw_bf, w2_bt, 1536, out, nullptr, 768, b2, out, 6);
}

// Round 10
// 260.376 us; speedup vs baseline: 1.0446x; 1.0446x over previous
//
#include <hip/hip_runtime.h>
#include <math.h>

// Problem constants: B=2, T=2048, D=768, H=12, HS=64, FF=3072, HALF=1536
#define TDIM 2048
#define DDIM 768
#define NH   12
#define NROWS 4096            // B*T
#define EPSV 1e-8f
#define SCALE 0.03608439182435161f   // 768^-0.5  (ref scales by D, not HS)

typedef __bf16 bf16_t;
typedef bf16_t bf16x8 __attribute__((ext_vector_type(8)));
typedef bf16_t bf16x4 __attribute__((ext_vector_type(4)));
typedef bf16_t bf16x2 __attribute__((ext_vector_type(2)));
typedef float  floatx4 __attribute__((ext_vector_type(4)));

// async global->LDS, 16B per lane; LDS dest = wave-uniform base + lane*16
__device__ __forceinline__ void glds16(const bf16_t* g, bf16_t* l) {
    __builtin_amdgcn_global_load_lds(
        (const __attribute__((address_space(1))) void*)g,
        (__attribute__((address_space(3))) void*)l, 16, 0, 0);
}

// ------- fused: weight repack (blocks 0..1439) + RMSNorm #1 (1440..5535) -----
// pack: 64x64 fp32->bf16 tile transpose. [0,144) Wo, [144,720) W1 (a/g
// column-interleaved for fused SwiGLU), [720,1008) W2, [1008,1440) QKV.
// rmsnorm: row = bid - 1440.
__global__ __launch_bounds__(256) void pack_rms(
    const float* __restrict__ Wq, const float* __restrict__ Wk,
    const float* __restrict__ Wv, const float* __restrict__ Wo,
    const float* __restrict__ W1, const float* __restrict__ W2,
    bf16_t* __restrict__ qkvw, bf16_t* __restrict__ wo,
    bf16_t* __restrict__ w1, bf16_t* __restrict__ w2,
    const float* __restrict__ x, const float* __restrict__ g1,
    bf16_t* __restrict__ hout)
{
    __shared__ float Ts[64][65];
    __shared__ float red[4];
    __shared__ float tot;
    int bid = blockIdx.x;
    int tid = threadIdx.x;

    if (bid >= 1440) {                     // ---- RMSNorm path ----
        int row = bid - 1440;
        const float* xr = x + (size_t)row * DDIM;
        float v0 = xr[tid], v1 = xr[tid + 256], v2 = xr[tid + 512];
        float s = v0*v0 + v1*v1 + v2*v2;
        #pragma unroll
        for (int off = 32; off > 0; off >>= 1)
            s += __shfl_down(s, off, 64);
        if ((tid & 63) == 0) red[tid >> 6] = s;
        __syncthreads();
        if (tid == 0) tot = red[0] + red[1] + red[2] + red[3];
        __syncthreads();
        float rms = sqrtf(tot * (1.0f / DDIM));
        float inv = 1.0f / (rms + EPSV);
        bf16_t* orow = hout + (size_t)row * DDIM;
        orow[tid]       = (bf16_t)(g1[tid]       * v0 * inv);
        orow[tid + 256] = (bf16_t)(g1[tid + 256] * v1 * inv);
        orow[tid + 512] = (bf16_t)(g1[tid + 512] * v2 * inv);
        return;
    }

    // ---- pack path ----
    const float* src; bf16_t* dst;
    int srcld, dstld, k0, n0;
    int remap = 0;
    if (bid < 144) {                       // Wo: K=768, N=768 (12x12)
        int kx = bid % 12, nx = bid / 12;
        src = Wo; dst = wo; srcld = 768; dstld = 768; k0 = kx * 64; n0 = nx * 64;
    } else if (bid < 720) {                // W1: K=768, N=3072 (12x48)
        int t = bid - 144; int kx = t % 12, nx = t / 12;
        src = W1; dst = w1; srcld = 3072; dstld = 768; k0 = kx * 64; n0 = nx * 64;
        remap = 1;                         // interleave a/gate columns
    } else if (bid < 1008) {               // W2: K=1536, N=768 (24x12)
        int t = bid - 720; int kx = t % 24, nx = t / 24;
        src = W2; dst = w2; srcld = 768; dstld = 1536; k0 = kx * 64; n0 = nx * 64;
    } else {                               // QKV: 36 mats (768x64), 12 k-tiles
        int t = bid - 1008; int kx = t % 12, y = t / 12;
        int sel = y / 12, h = y - sel * 12;
        src = ((sel == 0) ? Wq : (sel == 1) ? Wk : Wv) + (size_t)h * 768 * 64;
        dst = qkvw + (size_t)(sel * 768 + h * 64) * 768;
        srcld = 64; dstld = 768; k0 = kx * 64; n0 = 0;
    }
    int r = tid >> 2, c = (tid & 3) * 16;
    const float* s = src + (size_t)(k0 + r) * srcld + n0 + c;
    #pragma unroll
    for (int i = 0; i < 4; i++) {
        float4 t = *(const float4*)(s + i * 4);
        Ts[r][c + i*4 + 0] = t.x; Ts[r][c + i*4 + 1] = t.y;
        Ts[r][c + i*4 + 2] = t.z; Ts[r][c + i*4 + 3] = t.w;
    }
    __syncthreads();
    int n = tid >> 2, kk = (tid & 3) * 16;
    bf16x8 o0, o1;
    #pragma unroll
    for (int i = 0; i < 8; i++) {
        o0[i] = (bf16_t)Ts[kk + i][n];
        o1[i] = (bf16_t)Ts[kk + 8 + i][n];
    }
    int oc = n0 + n;
    if (remap) oc = (oc < 1536) ? (oc * 2) : ((oc - 1536) * 2 + 1);
    bf16_t* d = dst + (size_t)oc * dstld + k0 + kk;
    *(bf16x8*)d = o0;
    *(bf16x8*)(d + 8) = o1;
}

// ---------------- RMSNorm -> bf16 (second norm) ----------------
__global__ __launch_bounds__(256) void rmsnorm_bf(
    const float* __restrict__ x, const float* __restrict__ g,
    bf16_t* __restrict__ out)
{
    int row = blockIdx.x;
    int tid = threadIdx.x;
    const float* xr = x + (size_t)row * DDIM;
    float v0 = xr[tid], v1 = xr[tid + 256], v2 = xr[tid + 512];
    float s = v0*v0 + v1*v1 + v2*v2;
    #pragma unroll
    for (int off = 32; off > 0; off >>= 1)
        s += __shfl_down(s, off, 64);
    __shared__ float red[4];
    __shared__ float tot;
    if ((tid & 63) == 0) red[tid >> 6] = s;
    __syncthreads();
    if (tid == 0) tot = red[0] + red[1] + red[2] + red[3];
    __syncthreads();
    float rms = sqrtf(tot * (1.0f / DDIM));
    float inv = 1.0f / (rms + EPSV);
    bf16_t* orow = out + (size_t)row * DDIM;
    orow[tid]       = (bf16_t)(g[tid]       * v0 * inv);
    orow[tid + 256] = (bf16_t)(g[tid + 256] * v1 * inv);
    orow[tid + 512] = (bf16_t)(g[tid + 512] * v2 * inv);
}

// ---------------- bf16 MFMA GEMM, BK=64 twin-buffer, C^T epilogue ------------
// R6-exact (measured best). C[M x N] = A[M x K] * BT[N x K]^T. Tile TM x 128,
// 4 waves 2x2. 1-D grid + XCD swizzle (T1). The two-__syncthreads K-loop is
// the m97 structure: compiler self-schedules 16 ds_reads + 32 MFMAs; explicit
// pipelining attempts (R7: BK=32, 3-buf, vmcnt(4), sched_barrier pins)
// REGRESSED 30% (m141 failure mode) — do not reintroduce.
// EPI=0: bias/resid, fp32/bf16 out. EPI=1: fused SwiGLU (a/g interleaved BT).
template<int TM, int EPI>
__global__ __launch_bounds__(256) void gemm_bf16(
    const bf16_t* __restrict__ A, const bf16_t* __restrict__ BT, int K,
    float* __restrict__ Cf, bf16_t* __restrict__ Cb, int ldc,
    const float* __restrict__ bias, const float* __restrict__ resid, int gx)
{
    constexpr int MT = TM / 32;           // m-frags per wave (4 or 2)
    __shared__ bf16_t As0[TM][32], As1[TM][32];      // 64B rows (m97 layout)
    __shared__ bf16_t Bs0[128][32], Bs1[128][32];
    int tid = threadIdx.x;
    int wave = tid >> 6, lane = tid & 63;
    int lrow = lane & 15, quad = lane >> 4;
    int wm = wave >> 1, wn = wave & 1;

    // XCD swizzle: nwg % 8 == 0 for all launches
    int flat = blockIdx.x;
    int cpx = gridDim.x >> 3;
    int swz = (flat & 7) * cpx + (flat >> 3);
    int m0 = (swz / gx) * TM;
    int n0 = (swz % gx) * 128;

    int srow = lane >> 2, scol = (lane & 3) * 8;     // 16 rows x 8 elems per glds
    const bf16_t* Ag = A  + ((size_t)m0 + wave * (TM/4) + srow) * K + scol;
    const bf16_t* Bg = BT + ((size_t)n0 + wave * 32 + srow) * K + scol;

    floatx4 acc[MT][4];
    #pragma unroll
    for (int mt = 0; mt < MT; mt++)
        #pragma unroll
        for (int nt = 0; nt < 4; nt++)
            #pragma unroll
            for (int r = 0; r < 4; r++) acc[mt][nt][r] = 0.f;

    for (int k0 = 0; k0 < K; k0 += 64) {
        __syncthreads();
        #pragma unroll
        for (int i = 0; i < TM/64; i++) {            // 2 (TM=128) or 1 (TM=64)
            glds16(Ag + (size_t)(i*16) * K + k0,      &As0[wave*(TM/4) + i*16][0]);
            glds16(Ag + (size_t)(i*16) * K + k0 + 32, &As1[wave*(TM/4) + i*16][0]);
        }
        #pragma unroll
        for (int i = 0; i < 2; i++) {
            glds16(Bg + (size_t)(i*16) * K + k0,      &Bs0[wave*32 + i*16][0]);
            glds16(Bg + (size_t)(i*16) * K + k0 + 32, &Bs1[wave*32 + i*16][0]);
        }
        __syncthreads();

        bf16x8 af0[MT], af1[MT], bf0[4], bf1[4];
        #pragma unroll
        for (int mt = 0; mt < MT; mt++) {
            af0[mt] = *(const bf16x8*)&As0[wm*(TM/2) + mt*16 + lrow][quad * 8];
            af1[mt] = *(const bf16x8*)&As1[wm*(TM/2) + mt*16 + lrow][quad * 8];
        }
        #pragma unroll
        for (int nt = 0; nt < 4; nt++) {
            bf0[nt] = *(const bf16x8*)&Bs0[wn*64 + nt*16 + lrow][quad * 8];
            bf1[nt] = *(const bf16x8*)&Bs1[wn*64 + nt*16 + lrow][quad * 8];
        }
        #pragma unroll
        for (int mt = 0; mt < MT; mt++)
            #pragma unroll
            for (int nt = 0; nt < 4; nt++) {
                acc[mt][nt] = __builtin_amdgcn_mfma_f32_16x16x32_bf16(
                    bf0[nt], af0[mt], acc[mt][nt], 0, 0, 0);
                acc[mt][nt] = __builtin_amdgcn_mfma_f32_16x16x32_bf16(
                    bf1[nt], af1[mt], acc[mt][nt], 0, 0, 0);
            }
    }

    // epilogue (C^T layout): row = m0+wm*(TM/2)+mt*16+lrow,
    //                        col = n0+wn*64+nt*16+quad*4 .. +4
    int crow0 = m0 + wm * (TM/2);
    int ccol0 = n0 + wn * 64;
    #pragma unroll
    for (int mt = 0; mt < MT; mt++) {
        int row = crow0 + mt * 16 + lrow;
        #pragma unroll
        for (int nt = 0; nt < 4; nt++) {
            int col = ccol0 + nt * 16 + quad * 4;
            floatx4 a = acc[mt][nt];
            if constexpr (EPI == 1) {
                // cols = {a_c, g_c, a_{c+1}, g_{c+1}}, c = col/2
                int c = col >> 1;
                float2 ba = *(const float2*)(bias + c);
                float2 bg = *(const float2*)(bias + 1536 + c);
                float a0 = a[0] + ba.x, g0 = a[1] + bg.x;
                float a1 = a[2] + ba.y, g1 = a[3] + bg.y;
                bf16x2 v;
                v[0] = (bf16_t)(a0 * (g0 / (1.0f + __expf(-g0))));
                v[1] = (bf16_t)(a1 * (g1 / (1.0f + __expf(-g1))));
                *(bf16x2*)(Cb + (size_t)row * ldc + c) = v;
            } else {
                size_t off = (size_t)row * ldc + col;
                float4 bv = make_float4(0.f, 0.f, 0.f, 0.f);
                if (bias) bv = *(const float4*)(bias + col);
                float4 rs = make_float4(0.f, 0.f, 0.f, 0.f);
                if (resid) rs = *(const float4*)(resid + off);
                if (Cf) {
                    float4 v;
                    v.x = a[0] + bv.x + rs.x; v.y = a[1] + bv.y + rs.y;
                    v.z = a[2] + bv.z + rs.z; v.w = a[3] + bv.w + rs.w;
                    *(float4*)(Cf + off) = v;
                } else {
                    bf16x4 v;
                    v[0] = (bf16_t)(a[0] + bv.x + rs.x);
                    v[1] = (bf16_t)(a[1] + bv.y + rs.y);
                    v[2] = (bf16_t)(a[2] + bv.z + rs.z);
                    v[3] = (bf16_t)(a[3] + bv.w + rs.w);
                    *(bf16x4*)(Cb + off) = v;
                }
            }
        }
    }
}

// ---------------- V transpose: qkv V-part -> vt[bh][dim][t] ----------------
__global__ __launch_bounds__(256) void vt_kernel(
    const bf16_t* __restrict__ qkv, bf16_t* __restrict__ vt)
{
    __shared__ bf16_t Ts[64][72];
    int t0 = blockIdx.x * 64;
    int bh = blockIdx.y;
    int b = bh / NH, h = bh - b * NH;
    int tid = threadIdx.x;
    int r = tid >> 2, c = (tid & 3) * 16;
    const bf16_t* src = qkv + ((size_t)b * TDIM + t0 + r) * 2304 + 1536 + h * 64 + c;
    *(bf16x8*)&Ts[r][c]     = *(const bf16x8*)src;
    *(bf16x8*)&Ts[r][c + 8] = *(const bf16x8*)(src + 8);
    __syncthreads();
    int d = tid >> 2, tt = (tid & 3) * 16;
    bf16x8 o0, o1;
    #pragma unroll
    for (int i = 0; i < 8; i++) {
        o0[i] = Ts[tt + i][d];
        o1[i] = Ts[tt + 8 + i][d];
    }
    bf16_t* dst = vt + ((size_t)bh * 64 + d) * TDIM + t0 + tt;
    *(bf16x8*)dst = o0;
    *(bf16x8*)(dst + 8) = o1;
}

// ---------------- MFMA flash attention, S^T formulation ----------------
// v3 (parked — best measured attn variant, 44.8us). Balanced CU schedule:
// blocks {c, c+256, c+512} land on the same CU; qt triples sum to 46/47.
// Double-buffered K/V, reg-prefetch 2 tiles ahead, mid-loop write-late staging,
// lgkmcnt-only barrier, setprio on MFMA clusters, deferred rescale (THR=8).
// SIX structural variants (R0-R9) land 44.8-61us; v3 is the floor. The cost
// is the intrinsic per-iteration dependency chain (QK->softmax->PV->barrier),
// not any single pipe: v6 zeroed bank conflicts and cut FETCH 3x yet ran 35%
// slower (fewer blocks, heavier per-iter body). Keep v3.
__global__ __launch_bounds__(256) void attn_mfma(
    const bf16_t* __restrict__ qkv, const bf16_t* __restrict__ vt,
    bf16_t* __restrict__ o)
{
    const int QS = 2304;
    int bid = blockIdx.x;
    int c = bid & 255, slot = bid >> 8;
    int x = c & 31, g = c >> 5;
    int qt, bh;
    if (slot == 0)      { bh = g;      qt = x; }
    else if (slot == 1) { bh = 8 + g;  qt = (x + 16) & 31; }
    else                { bh = 16 + g; qt = (x < 16) ? (31 - 2 * x) : (62 - 2 * x); }
    int b = bh / NH, h = bh - b * NH;
    int tid = threadIdx.x;
    int wave = tid >> 6, lane = tid & 63;
    int lrow = lane & 15, quad = lane >> 4;

    __shared__ bf16_t Ks[2][64][72];      // K tile: row = kcol, col = dim
    __shared__ bf16_t Vts[2][64][72];     // V^T: row = dim, col = kcol
    __shared__ bf16_t Ps[4][16][72];      // per-wave P (row = q, col = kc)

    size_t rbase = (size_t)b * TDIM;
    int q0 = qt * 64, qrow_w = q0 + wave * 16;

    const bf16_t* qp = qkv + (rbase + qrow_w + lrow) * QS + h * 64;
    bf16x8 qf[2];
    qf[0] = *(const bf16x8*)(qp + quad * 8);
    qf[1] = *(const bf16x8*)(qp + 32 + quad * 8);

    floatx4 o_acc[4];   // O^T: (dim = mt*16 + quad*4 + r, q = lrow)
    #pragma unroll
    for (int mt = 0; mt < 4; mt++)
        #pragma unroll
        for (int r = 0; r < 4; r++) o_acc[mt][r] = 0.f;
    float m_r = -INFINITY, l_r = 0.f;

    int srow = tid >> 2;            // 0..63
    int scol = (tid & 3) * 16;      // 0,16,32,48
    const bf16_t* kbase = qkv + (rbase + srow) * QS + 768 + h * 64 + scol;
    const bf16_t* vbase = vt + ((size_t)bh * 64 + srow) * TDIM + scol;

    // prologue: tile 0 -> LDS buf0; issue prefetch of tile 1 into regs
    bf16x8 kr0 = *(const bf16x8*)kbase;
    bf16x8 kr1 = *(const bf16x8*)(kbase + 8);
    bf16x8 vr0 = *(const bf16x8*)vbase;
    bf16x8 vr1 = *(const bf16x8*)(vbase + 8);
    *(bf16x8*)&Ks[0][srow][scol]      = kr0;
    *(bf16x8*)&Ks[0][srow][scol + 8]  = kr1;
    *(bf16x8*)&Vts[0][srow][scol]     = vr0;
    *(bf16x8*)&Vts[0][srow][scol + 8] = vr1;
    if (qt >= 1) {
        const bf16_t* kp = kbase + (size_t)64 * QS;
        const bf16_t* vp = vbase + 64;
        kr0 = *(const bf16x8*)kp;  kr1 = *(const bf16x8*)(kp + 8);
        vr0 = *(const bf16x8*)vp;  vr1 = *(const bf16x8*)(vp + 8);
    }
    asm volatile("s_waitcnt lgkmcnt(0)" ::: "memory");
    __builtin_amdgcn_s_barrier();

    for (int s = 0; s <= qt; s++) {
        int cur = s & 1;

        // S^T = K Q^T : C row = kc (nt*16 + quad*4 + r), col = q (lrow)
        floatx4 sfrag[4];
        __builtin_amdgcn_s_setprio(1);
        #pragma unroll
        for (int nt = 0; nt < 4; nt++) {
            floatx4 a;
            #pragma unroll
            for (int r = 0; r < 4; r++) a[r] = 0.f;
            #pragma unroll
            for (int kf = 0; kf < 2; kf++) {
                bf16x8 afr = *(const bf16x8*)&Ks[cur][nt * 16 + lrow][kf * 32 + quad * 8];
                a = __builtin_amdgcn_mfma_f32_16x16x32_bf16(afr, qf[kf], a, 0, 0, 0);
            }
            sfrag[nt] = a;
        }
        __builtin_amdgcn_s_setprio(0);

        // write-late: stage tile s+1 (regs loaded an iteration ago) into the
        // idle buffer — other waves are only reading buf[cur], no barrier needed
        if (s < qt) {
            int nxt = cur ^ 1;
            *(bf16x8*)&Ks[nxt][srow][scol]      = kr0;
            *(bf16x8*)&Ks[nxt][srow][scol + 8]  = kr1;
            *(bf16x8*)&Vts[nxt][srow][scol]     = vr0;
            *(bf16x8*)&Vts[nxt][srow][scol + 8] = vr1;
        }

        if (s == qt) {
            int qg = qrow_w + lrow;
            #pragma unroll
            for (int nt = 0; nt < 4; nt++)
                #pragma unroll
                for (int r = 0; r < 4; r++) {
                    int kc = s * 64 + nt * 16 + quad * 4 + r;
                    sfrag[nt][r] = (kc > qg) ? -INFINITY : sfrag[nt][r] * SCALE;
                }
        } else {
            #pragma unroll
            for (int nt = 0; nt < 4; nt++)
                #pragma unroll
                for (int r = 0; r < 4; r++) sfrag[nt][r] *= SCALE;
        }

        // online softmax over kc: reg-max + 2 shfls, deferred rescale (THR=8)
        float mx = sfrag[0][0];
        #pragma unroll
        for (int nt = 0; nt < 4; nt++)
            #pragma unroll
            for (int r = 0; r < 4; r++) mx = fmaxf(mx, sfrag[nt][r]);
        mx = fmaxf(mx, __shfl_xor(mx, 16, 64));
        mx = fmaxf(mx, __shfl_xor(mx, 32, 64));
        if (__any(mx > m_r + 8.0f)) {
            float mn = fmaxf(m_r, mx);
            float alpha = __expf(m_r - mn);
            m_r = mn;
            l_r *= alpha;
            #pragma unroll
            for (int mt = 0; mt < 4; mt++)
                #pragma unroll
                for (int r = 0; r < 4; r++) o_acc[mt][r] *= alpha;
        }

        float ls = 0.f;
        #pragma unroll
        for (int nt = 0; nt < 4; nt++) {
            bf16x4 pv;
            #pragma unroll
            for (int r = 0; r < 4; r++) {
                float p = __expf(sfrag[nt][r] - m_r);
                ls += p;
                pv[r] = (bf16_t)p;
            }
            *(bf16x4*)&Ps[wave][lrow][nt * 16 + quad * 4] = pv;
        }
        ls += __shfl_xor(ls, 16, 64);
        ls += __shfl_xor(ls, 32, 64);
        l_r += ls;

        // O^T += V^T P^T (wave-private Ps: no barrier needed)
        __builtin_amdgcn_s_setprio(1);
        #pragma unroll
        for (int kf = 0; kf < 2; kf++) {
            bf16x8 pfr = *(const bf16x8*)&Ps[wave][lrow][kf * 32 + quad * 8];
            #pragma unroll
            for (int mt = 0; mt < 4; mt++) {
                bf16x8 vfr = *(const bf16x8*)&Vts[cur][mt * 16 + lrow][kf * 32 + quad * 8];
                o_acc[mt] = __builtin_amdgcn_mfma_f32_16x16x32_bf16(vfr, pfr, o_acc[mt], 0, 0, 0);
            }
        }
        __builtin_amdgcn_s_setprio(0);

        // issue-early: global loads for tile s+2 (consumed next iteration)
        if (s + 2 <= qt) {
            const bf16_t* kp = kbase + (size_t)(s + 2) * 64 * QS;
            const bf16_t* vp = vbase + (size_t)(s + 2) * 64;
            kr0 = *(const bf16x8*)kp;  kr1 = *(const bf16x8*)(kp + 8);
            vr0 = *(const bf16x8*)vp;  vr1 = *(const bf16x8*)(vp + 8);
        }

        // LDS-only fence + raw barrier: keep the global prefetch in flight
        asm volatile("s_waitcnt lgkmcnt(0)" ::: "memory");
        __builtin_amdgcn_s_barrier();
    }

    float inv = 1.0f / l_r;
    size_t rb = (rbase + qrow_w + lrow) * DDIM + h * 64;
    #pragma unroll
    for (int mt = 0; mt < 4; mt++) {
        bf16x4 ov;
        #pragma unroll
        for (int r = 0; r < 4; r++) ov[r] = (bf16_t)(o_acc[mt][r] * inv);
        *(bf16x4*)(o + rb + mt * 16 + quad * 4) = ov;
    }
}

extern "C" void kernel_launch(void* const* d_in, const int* in_sizes, int n_in,
                              void* d_out, int out_size, void* d_ws, size_t ws_size,
                              hipStream_t stream) {
    const float* x  = (const float*)d_in[0];
    const float* Wq = (const float*)d_in[1];
    const float* Wk = (const float*)d_in[2];
    const float* Wv = (const float*)d_in[3];
    const float* Wo = (const float*)d_in[4];
    const float* bo = (const float*)d_in[5];
    const float* W1 = (const float*)d_in[6];
    const float* b1 = (const float*)d_in[7];
    const float* W2 = (const float*)d_in[8];
    const float* b2 = (const float*)d_in[9];
    const float* g1 = (const float*)d_in[10];
    const float* g2 = (const float*)d_in[11];
    float* out = (float*)d_out;
    char* ws = (char*)d_ws;

    bf16_t* qkvw_bt = (bf16_t*)(ws);                    // 2304x768
    bf16_t* wo_bt   = (bf16_t*)(ws + 3538944);          // 768x768
    bf16_t* w1_bt   = (bf16_t*)(ws + 4718592);          // 3072x768 (interleaved)
    bf16_t* w2_bt   = (bf16_t*)(ws + 9437184);          // 768x1536
    bf16_t* h_bf    = (bf16_t*)(ws + 11796480);         // 4096x768
    bf16_t* qkv     = (bf16_t*)(ws + 18087936);         // 4096x2304
    bf16_t* attn_bf = (bf16_t*)(ws + 36962304);         // 4096x768
    bf16_t* sw_bf   = (bf16_t*)(ws + 68419584);         // 4096x1536
    bf16_t* vt      = (bf16_t*)(ws + 81002496);         // 24x64x2048

    // fused: weight pack (1440 blocks) + rmsnorm #1 (4096 blocks)
    pack_rms<<<5536, 256, 0, stream>>>(Wq, Wk, Wv, Wo, W1, W2,
                                       qkvw_bt, wo_bt, w1_bt, w2_bt,
                                       x, g1, h_bf);

    // qkv = h @ [Wq|Wk|Wv]  (4096 x 2304 bf16): 18x32 -> 576 blocks
    gemm_bf16<128, 0><<<576, 256, 0, stream>>>(
        h_bf, qkvw_bt, 768, nullptr, qkv, 2304, nullptr, nullptr, 18);

    vt_kernel<<<dim3(32, 24), 256, 0, stream>>>(qkv, vt);

    attn_mfma<<<768, 256, 0, stream>>>(qkv, vt, attn_bf);

    // out = x + attn @ Wo + bo  (fp32): 6x64 -> 384 blocks
    gemm_bf16<64, 0><<<384, 256, 0, stream>>>(
        attn_bf, wo_bt, 768, out, nullptr, 768, bo, x, 6);

    rmsnorm_bf<<<NROWS, 256, 0, stream>>>(out, g2, h_bf);

    // sw = silu(gate) * a, fused into the W1 GEMM epilogue: 24x32 -> 768 blocks
    gemm_bf16<128, 1><<<768, 256, 0, stream>>>(
        h_bf, w1_bt, 768, nullptr, sw_bf, 1536, b1, nullptr, 24);

    // out = out + sw @ W2 + b2  (fp32): 6x64 -> 384 blocks
    gemm_bf16<64, 0><<<384, 256, 0, stream>>>(
        sw_bf, w2_bt, 1536, out, nullptr, 768, b2, out, 6);
}

// Round 11
// 252.933 us; speedup vs baseline: 1.0753x; 1.0294x over previous
//
#include <hip/hip_runtime.h>
#include <math.h>

// Problem constants: B=2, T=2048, D=768, H=12, HS=64, FF=3072, HALF=1536
#define TDIM 2048
#define DDIM 768
#define NH   12
#define NROWS 4096            // B*T
#define EPSV 1e-8f
#define SCALE 0.03608439182435161f   // 768^-0.5  (ref scales by D, not HS)

typedef __bf16 bf16_t;
typedef bf16_t bf16x8 __attribute__((ext_vector_type(8)));
typedef bf16_t bf16x4 __attribute__((ext_vector_type(4)));
typedef bf16_t bf16x2 __attribute__((ext_vector_type(2)));
typedef float  floatx4 __attribute__((ext_vector_type(4)));

// async global->LDS, 16B per lane; LDS dest = wave-uniform base + lane*16
__device__ __forceinline__ void glds16(const bf16_t* g, bf16_t* l) {
    __builtin_amdgcn_global_load_lds(
        (const __attribute__((address_space(1))) void*)g,
        (__attribute__((address_space(3))) void*)l, 16, 0, 0);
}

// ------- fused: weight repack (blocks 0..1439) + RMSNorm #1 (1440..5535) -----
// pack: 64x64 fp32->bf16 tile transpose. [0,144) Wo, [144,720) W1 (a/g
// column-interleaved for fused SwiGLU), [720,1008) W2, [1008,1440) QKV.
// rmsnorm: row = bid - 1440.
__global__ __launch_bounds__(256) void pack_rms(
    const float* __restrict__ Wq, const float* __restrict__ Wk,
    const float* __restrict__ Wv, const float* __restrict__ Wo,
    const float* __restrict__ W1, const float* __restrict__ W2,
    bf16_t* __restrict__ qkvw, bf16_t* __restrict__ wo,
    bf16_t* __restrict__ w1, bf16_t* __restrict__ w2,
    const float* __restrict__ x, const float* __restrict__ g1,
    bf16_t* __restrict__ hout)
{
    __shared__ float Ts[64][65];
    __shared__ float red[4];
    __shared__ float tot;
    int bid = blockIdx.x;
    int tid = threadIdx.x;

    if (bid >= 1440) {                     // ---- RMSNorm path ----
        int row = bid - 1440;
        const float* xr = x + (size_t)row * DDIM;
        float v0 = xr[tid], v1 = xr[tid + 256], v2 = xr[tid + 512];
        float s = v0*v0 + v1*v1 + v2*v2;
        #pragma unroll
        for (int off = 32; off > 0; off >>= 1)
            s += __shfl_down(s, off, 64);
        if ((tid & 63) == 0) red[tid >> 6] = s;
        __syncthreads();
        if (tid == 0) tot = red[0] + red[1] + red[2] + red[3];
        __syncthreads();
        float rms = sqrtf(tot * (1.0f / DDIM));
        float inv = 1.0f / (rms + EPSV);
        bf16_t* orow = hout + (size_t)row * DDIM;
        orow[tid]       = (bf16_t)(g1[tid]       * v0 * inv);
        orow[tid + 256] = (bf16_t)(g1[tid + 256] * v1 * inv);
        orow[tid + 512] = (bf16_t)(g1[tid + 512] * v2 * inv);
        return;
    }

    // ---- pack path ----
    const float* src; bf16_t* dst;
    int srcld, dstld, k0, n0;
    int remap = 0;
    if (bid < 144) {                       // Wo: K=768, N=768 (12x12)
        int kx = bid % 12, nx = bid / 12;
        src = Wo; dst = wo; srcld = 768; dstld = 768; k0 = kx * 64; n0 = nx * 64;
    } else if (bid < 720) {                // W1: K=768, N=3072 (12x48)
        int t = bid - 144; int kx = t % 12, nx = t / 12;
        src = W1; dst = w1; srcld = 3072; dstld = 768; k0 = kx * 64; n0 = nx * 64;
        remap = 1;                         // interleave a/gate columns
    } else if (bid < 1008) {               // W2: K=1536, N=768 (24x12)
        int t = bid - 720; int kx = t % 24, nx = t / 24;
        src = W2; dst = w2; srcld = 768; dstld = 1536; k0 = kx * 64; n0 = nx * 64;
    } else {                               // QKV: 36 mats (768x64), 12 k-tiles
        int t = bid - 1008; int kx = t % 12, y = t / 12;
        int sel = y / 12, h = y - sel * 12;
        src = ((sel == 0) ? Wq : (sel == 1) ? Wk : Wv) + (size_t)h * 768 * 64;
        dst = qkvw + (size_t)(sel * 768 + h * 64) * 768;
        srcld = 64; dstld = 768; k0 = kx * 64; n0 = 0;
    }
    int r = tid >> 2, c = (tid & 3) * 16;
    const float* s = src + (size_t)(k0 + r) * srcld + n0 + c;
    #pragma unroll
    for (int i = 0; i < 4; i++) {
        float4 t = *(const float4*)(s + i * 4);
        Ts[r][c + i*4 + 0] = t.x; Ts[r][c + i*4 + 1] = t.y;
        Ts[r][c + i*4 + 2] = t.z; Ts[r][c + i*4 + 3] = t.w;
    }
    __syncthreads();
    int n = tid >> 2, kk = (tid & 3) * 16;
    bf16x8 o0, o1;
    #pragma unroll
    for (int i = 0; i < 8; i++) {
        o0[i] = (bf16_t)Ts[kk + i][n];
        o1[i] = (bf16_t)Ts[kk + 8 + i][n];
    }
    int oc = n0 + n;
    if (remap) oc = (oc < 1536) ? (oc * 2) : ((oc - 1536) * 2 + 1);
    bf16_t* d = dst + (size_t)oc * dstld + k0 + kk;
    *(bf16x8*)d = o0;
    *(bf16x8*)(d + 8) = o1;
}

// ---------------- RMSNorm -> bf16 (second norm) ----------------
__global__ __launch_bounds__(256) void rmsnorm_bf(
    const float* __restrict__ x, const float* __restrict__ g,
    bf16_t* __restrict__ out)
{
    int row = blockIdx.x;
    int tid = threadIdx.x;
    const float* xr = x + (size_t)row * DDIM;
    float v0 = xr[tid], v1 = xr[tid + 256], v2 = xr[tid + 512];
    float s = v0*v0 + v1*v1 + v2*v2;
    #pragma unroll
    for (int off = 32; off > 0; off >>= 1)
        s += __shfl_down(s, off, 64);
    __shared__ float red[4];
    __shared__ float tot;
    if ((tid & 63) == 0) red[tid >> 6] = s;
    __syncthreads();
    if (tid == 0) tot = red[0] + red[1] + red[2] + red[3];
    __syncthreads();
    float rms = sqrtf(tot * (1.0f / DDIM));
    float inv = 1.0f / (rms + EPSV);
    bf16_t* orow = out + (size_t)row * DDIM;
    orow[tid]       = (bf16_t)(g[tid]       * v0 * inv);
    orow[tid + 256] = (bf16_t)(g[tid + 256] * v1 * inv);
    orow[tid + 512] = (bf16_t)(g[tid + 512] * v2 * inv);
}

// ---------------- bf16 MFMA GEMM, BK=64 twin-buffer, C^T epilogue ------------
// R6-exact K-loop (measured best). C[M x N] = A[M x K] * BT[N x K]^T.
// Tile TM x 128, 4 waves 2x2. 1-D grid + XCD swizzle (T1). Explicit pipelining
// REGRESSED 30% (R7, m141 failure mode) — do not reintroduce.
// EPI=0: bias/resid, fp32/bf16 out. EPI=1: fused SwiGLU (a/g interleaved BT).
// EPI=2 (qkv): cols <1536 -> qkv buffer; cols >=1536 are V -> written
// TRANSPOSED into vt[bh][d][t], absorbing the old vt_kernel (block-uniform
// branch: 1536 % 128 == 0, so each block is pure-QK or pure-V).
template<int TM, int EPI>
__global__ __launch_bounds__(256) void gemm_bf16(
    const bf16_t* __restrict__ A, const bf16_t* __restrict__ BT, int K,
    float* __restrict__ Cf, bf16_t* __restrict__ Cb, int ldc,
    const float* __restrict__ bias, const float* __restrict__ resid, int gx,
    bf16_t* __restrict__ vtout)
{
    constexpr int MT = TM / 32;           // m-frags per wave (4 or 2)
    __shared__ bf16_t As0[TM][32], As1[TM][32];      // 64B rows (m97 layout)
    __shared__ bf16_t Bs0[128][32], Bs1[128][32];
    int tid = threadIdx.x;
    int wave = tid >> 6, lane = tid & 63;
    int lrow = lane & 15, quad = lane >> 4;
    int wm = wave >> 1, wn = wave & 1;

    // XCD swizzle: nwg % 8 == 0 for all launches
    int flat = blockIdx.x;
    int cpx = gridDim.x >> 3;
    int swz = (flat & 7) * cpx + (flat >> 3);
    int m0 = (swz / gx) * TM;
    int n0 = (swz % gx) * 128;

    int srow = lane >> 2, scol = (lane & 3) * 8;     // 16 rows x 8 elems per glds
    const bf16_t* Ag = A  + ((size_t)m0 + wave * (TM/4) + srow) * K + scol;
    const bf16_t* Bg = BT + ((size_t)n0 + wave * 32 + srow) * K + scol;

    floatx4 acc[MT][4];
    #pragma unroll
    for (int mt = 0; mt < MT; mt++)
        #pragma unroll
        for (int nt = 0; nt < 4; nt++)
            #pragma unroll
            for (int r = 0; r < 4; r++) acc[mt][nt][r] = 0.f;

    for (int k0 = 0; k0 < K; k0 += 64) {
        __syncthreads();
        #pragma unroll
        for (int i = 0; i < TM/64; i++) {            // 2 (TM=128) or 1 (TM=64)
            glds16(Ag + (size_t)(i*16) * K + k0,      &As0[wave*(TM/4) + i*16][0]);
            glds16(Ag + (size_t)(i*16) * K + k0 + 32, &As1[wave*(TM/4) + i*16][0]);
        }
        #pragma unroll
        for (int i = 0; i < 2; i++) {
            glds16(Bg + (size_t)(i*16) * K + k0,      &Bs0[wave*32 + i*16][0]);
            glds16(Bg + (size_t)(i*16) * K + k0 + 32, &Bs1[wave*32 + i*16][0]);
        }
        __syncthreads();

        bf16x8 af0[MT], af1[MT], bf0[4], bf1[4];
        #pragma unroll
        for (int mt = 0; mt < MT; mt++) {
            af0[mt] = *(const bf16x8*)&As0[wm*(TM/2) + mt*16 + lrow][quad * 8];
            af1[mt] = *(const bf16x8*)&As1[wm*(TM/2) + mt*16 + lrow][quad * 8];
        }
        #pragma unroll
        for (int nt = 0; nt < 4; nt++) {
            bf0[nt] = *(const bf16x8*)&Bs0[wn*64 + nt*16 + lrow][quad * 8];
            bf1[nt] = *(const bf16x8*)&Bs1[wn*64 + nt*16 + lrow][quad * 8];
        }
        #pragma unroll
        for (int mt = 0; mt < MT; mt++)
            #pragma unroll
            for (int nt = 0; nt < 4; nt++) {
                acc[mt][nt] = __builtin_amdgcn_mfma_f32_16x16x32_bf16(
                    bf0[nt], af0[mt], acc[mt][nt], 0, 0, 0);
                acc[mt][nt] = __builtin_amdgcn_mfma_f32_16x16x32_bf16(
                    bf1[nt], af1[mt], acc[mt][nt], 0, 0, 0);
            }
    }

    // epilogue (C^T layout): row = m0+wm*(TM/2)+mt*16+lrow,
    //                        col = n0+wn*64+nt*16+quad*4 .. +4
    int crow0 = m0 + wm * (TM/2);
    int ccol0 = n0 + wn * 64;
    #pragma unroll
    for (int mt = 0; mt < MT; mt++) {
        int row = crow0 + mt * 16 + lrow;
        #pragma unroll
        for (int nt = 0; nt < 4; nt++) {
            int col = ccol0 + nt * 16 + quad * 4;
            floatx4 a = acc[mt][nt];
            if constexpr (EPI == 1) {
                // cols = {a_c, g_c, a_{c+1}, g_{c+1}}, c = col/2
                int c = col >> 1;
                float2 ba = *(const float2*)(bias + c);
                float2 bg = *(const float2*)(bias + 1536 + c);
                float a0 = a[0] + ba.x, g0 = a[1] + bg.x;
                float a1 = a[2] + ba.y, g1 = a[3] + bg.y;
                bf16x2 v;
                v[0] = (bf16_t)(a0 * (g0 / (1.0f + __expf(-g0))));
                v[1] = (bf16_t)(a1 * (g1 / (1.0f + __expf(-g1))));
                *(bf16x2*)(Cb + (size_t)row * ldc + c) = v;
            } else if constexpr (EPI == 2) {
                if (col < 1536) {              // Q/K part -> qkv buffer
                    bf16x4 v;
                    v[0] = (bf16_t)a[0]; v[1] = (bf16_t)a[1];
                    v[2] = (bf16_t)a[2]; v[3] = (bf16_t)a[3];
                    *(bf16x4*)(Cb + (size_t)row * ldc + col) = v;
                } else {                       // V part -> vt[bh][d][t]
                    int vcol = col - 1536;
                    int hh = vcol >> 6, d0 = vcol & 63;
                    int bb = row >> 11, tt = row & 2047;
                    bf16_t* vbase2 = vtout +
                        ((size_t)(bb * NH + hh) * 64 + d0) * TDIM + tt;
                    #pragma unroll
                    for (int r = 0; r < 4; r++)
                        vbase2[(size_t)r * TDIM] = (bf16_t)a[r];
                }
            } else {
                size_t off = (size_t)row * ldc + col;
                float4 bv = make_float4(0.f, 0.f, 0.f, 0.f);
                if (bias) bv = *(const float4*)(bias + col);
                float4 rs = make_float4(0.f, 0.f, 0.f, 0.f);
                if (resid) rs = *(const float4*)(resid + off);
                if (Cf) {
                    float4 v;
                    v.x = a[0] + bv.x + rs.x; v.y = a[1] + bv.y + rs.y;
                    v.z = a[2] + bv.z + rs.z; v.w = a[3] + bv.w + rs.w;
                    *(float4*)(Cf + off) = v;
                } else {
                    bf16x4 v;
                    v[0] = (bf16_t)(a[0] + bv.x + rs.x);
                    v[1] = (bf16_t)(a[1] + bv.y + rs.y);
                    v[2] = (bf16_t)(a[2] + bv.z + rs.z);
                    v[3] = (bf16_t)(a[3] + bv.w + rs.w);
                    *(bf16x4*)(Cb + off) = v;
                }
            }
        }
    }
}

// ---------------- MFMA flash attention, S^T formulation ----------------
// v3 (parked — best measured attn variant, 44.8us). Balanced CU schedule:
// blocks {c, c+256, c+512} land on the same CU; qt triples sum to 46/47.
// Double-buffered K/V, reg-prefetch 2 tiles ahead, mid-loop write-late staging,
// lgkmcnt-only barrier, setprio on MFMA clusters, deferred rescale (THR=8).
// SIX structural variants (R0-R9) land 44.8-61us; v3 is the floor. The cost
// is the intrinsic per-iteration dependency chain (QK->softmax->PV->barrier),
// not any single pipe: v6 zeroed bank conflicts and cut FETCH 3x yet ran 35%
// slower (fewer blocks, heavier per-iter body). Keep v3.
__global__ __launch_bounds__(256) void attn_mfma(
    const bf16_t* __restrict__ qkv, const bf16_t* __restrict__ vt,
    bf16_t* __restrict__ o)
{
    const int QS = 2304;
    int bid = blockIdx.x;
    int c = bid & 255, slot = bid >> 8;
    int x = c & 31, g = c >> 5;
    int qt, bh;
    if (slot == 0)      { bh = g;      qt = x; }
    else if (slot == 1) { bh = 8 + g;  qt = (x + 16) & 31; }
    else                { bh = 16 + g; qt = (x < 16) ? (31 - 2 * x) : (62 - 2 * x); }
    int b = bh / NH, h = bh - b * NH;
    int tid = threadIdx.x;
    int wave = tid >> 6, lane = tid & 63;
    int lrow = lane & 15, quad = lane >> 4;

    __shared__ bf16_t Ks[2][64][72];      // K tile: row = kcol, col = dim
    __shared__ bf16_t Vts[2][64][72];     // V^T: row = dim, col = kcol
    __shared__ bf16_t Ps[4][16][72];      // per-wave P (row = q, col = kc)

    size_t rbase = (size_t)b * TDIM;
    int q0 = qt * 64, qrow_w = q0 + wave * 16;

    const bf16_t* qp = qkv + (rbase + qrow_w + lrow) * QS + h * 64;
    bf16x8 qf[2];
    qf[0] = *(const bf16x8*)(qp + quad * 8);
    qf[1] = *(const bf16x8*)(qp + 32 + quad * 8);

    floatx4 o_acc[4];   // O^T: (dim = mt*16 + quad*4 + r, q = lrow)
    #pragma unroll
    for (int mt = 0; mt < 4; mt++)
        #pragma unroll
        for (int r = 0; r < 4; r++) o_acc[mt][r] = 0.f;
    float m_r = -INFINITY, l_r = 0.f;

    int srow = tid >> 2;            // 0..63
    int scol = (tid & 3) * 16;      // 0,16,32,48
    const bf16_t* kbase = qkv + (rbase + srow) * QS + 768 + h * 64 + scol;
    const bf16_t* vbase = vt + ((size_t)bh * 64 + srow) * TDIM + scol;

    // prologue: tile 0 -> LDS buf0; issue prefetch of tile 1 into regs
    bf16x8 kr0 = *(const bf16x8*)kbase;
    bf16x8 kr1 = *(const bf16x8*)(kbase + 8);
    bf16x8 vr0 = *(const bf16x8*)vbase;
    bf16x8 vr1 = *(const bf16x8*)(vbase + 8);
    *(bf16x8*)&Ks[0][srow][scol]      = kr0;
    *(bf16x8*)&Ks[0][srow][scol + 8]  = kr1;
    *(bf16x8*)&Vts[0][srow][scol]     = vr0;
    *(bf16x8*)&Vts[0][srow][scol + 8] = vr1;
    if (qt >= 1) {
        const bf16_t* kp = kbase + (size_t)64 * QS;
        const bf16_t* vp = vbase + 64;
        kr0 = *(const bf16x8*)kp;  kr1 = *(const bf16x8*)(kp + 8);
        vr0 = *(const bf16x8*)vp;  vr1 = *(const bf16x8*)(vp + 8);
    }
    asm volatile("s_waitcnt lgkmcnt(0)" ::: "memory");
    __builtin_amdgcn_s_barrier();

    for (int s = 0; s <= qt; s++) {
        int cur = s & 1;

        // S^T = K Q^T : C row = kc (nt*16 + quad*4 + r), col = q (lrow)
        floatx4 sfrag[4];
        __builtin_amdgcn_s_setprio(1);
        #pragma unroll
        for (int nt = 0; nt < 4; nt++) {
            floatx4 a;
            #pragma unroll
            for (int r = 0; r < 4; r++) a[r] = 0.f;
            #pragma unroll
            for (int kf = 0; kf < 2; kf++) {
                bf16x8 afr = *(const bf16x8*)&Ks[cur][nt * 16 + lrow][kf * 32 + quad * 8];
                a = __builtin_amdgcn_mfma_f32_16x16x32_bf16(afr, qf[kf], a, 0, 0, 0);
            }
            sfrag[nt] = a;
        }
        __builtin_amdgcn_s_setprio(0);

        // write-late: stage tile s+1 (regs loaded an iteration ago) into the
        // idle buffer — other waves are only reading buf[cur], no barrier needed
        if (s < qt) {
            int nxt = cur ^ 1;
            *(bf16x8*)&Ks[nxt][srow][scol]      = kr0;
            *(bf16x8*)&Ks[nxt][srow][scol + 8]  = kr1;
            *(bf16x8*)&Vts[nxt][srow][scol]     = vr0;
            *(bf16x8*)&Vts[nxt][srow][scol + 8] = vr1;
        }

        if (s == qt) {
            int qg = qrow_w + lrow;
            #pragma unroll
            for (int nt = 0; nt < 4; nt++)
                #pragma unroll
                for (int r = 0; r < 4; r++) {
                    int kc = s * 64 + nt * 16 + quad * 4 + r;
                    sfrag[nt][r] = (kc > qg) ? -INFINITY : sfrag[nt][r] * SCALE;
                }
        } else {
            #pragma unroll
            for (int nt = 0; nt < 4; nt++)
                #pragma unroll
                for (int r = 0; r < 4; r++) sfrag[nt][r] *= SCALE;
        }

        // online softmax over kc: reg-max + 2 shfls, deferred rescale (THR=8)
        float mx = sfrag[0][0];
        #pragma unroll
        for (int nt = 0; nt < 4; nt++)
            #pragma unroll
            for (int r = 0; r < 4; r++) mx = fmaxf(mx, sfrag[nt][r]);
        mx = fmaxf(mx, __shfl_xor(mx, 16, 64));
        mx = fmaxf(mx, __shfl_xor(mx, 32, 64));
        if (__any(mx > m_r + 8.0f)) {
            float mn = fmaxf(m_r, mx);
            float alpha = __expf(m_r - mn);
            m_r = mn;
            l_r *= alpha;
            #pragma unroll
            for (int mt = 0; mt < 4; mt++)
                #pragma unroll
                for (int r = 0; r < 4; r++) o_acc[mt][r] *= alpha;
        }

        float ls = 0.f;
        #pragma unroll
        for (int nt = 0; nt < 4; nt++) {
            bf16x4 pv;
            #pragma unroll
            for (int r = 0; r < 4; r++) {
                float p = __expf(sfrag[nt][r] - m_r);
                ls += p;
                pv[r] = (bf16_t)p;
            }
            *(bf16x4*)&Ps[wave][lrow][nt * 16 + quad * 4] = pv;
        }
        ls += __shfl_xor(ls, 16, 64);
        ls += __shfl_xor(ls, 32, 64);
        l_r += ls;

        // O^T += V^T P^T (wave-private Ps: no barrier needed)
        __builtin_amdgcn_s_setprio(1);
        #pragma unroll
        for (int kf = 0; kf < 2; kf++) {
            bf16x8 pfr = *(const bf16x8*)&Ps[wave][lrow][kf * 32 + quad * 8];
            #pragma unroll
            for (int mt = 0; mt < 4; mt++) {
                bf16x8 vfr = *(const bf16x8*)&Vts[cur][mt * 16 + lrow][kf * 32 + quad * 8];
                o_acc[mt] = __builtin_amdgcn_mfma_f32_16x16x32_bf16(vfr, pfr, o_acc[mt], 0, 0, 0);
            }
        }
        __builtin_amdgcn_s_setprio(0);

        // issue-early: global loads for tile s+2 (consumed next iteration)
        if (s + 2 <= qt) {
            const bf16_t* kp = kbase + (size_t)(s + 2) * 64 * QS;
            const bf16_t* vp = vbase + (size_t)(s + 2) * 64;
            kr0 = *(const bf16x8*)kp;  kr1 = *(const bf16x8*)(kp + 8);
            vr0 = *(const bf16x8*)vp;  vr1 = *(const bf16x8*)(vp + 8);
        }

        // LDS-only fence + raw barrier: keep the global prefetch in flight
        asm volatile("s_waitcnt lgkmcnt(0)" ::: "memory");
        __builtin_amdgcn_s_barrier();
    }

    float inv = 1.0f / l_r;
    size_t rb = (rbase + qrow_w + lrow) * DDIM + h * 64;
    #pragma unroll
    for (int mt = 0; mt < 4; mt++) {
        bf16x4 ov;
        #pragma unroll
        for (int r = 0; r < 4; r++) ov[r] = (bf16_t)(o_acc[mt][r] * inv);
        *(bf16x4*)(o + rb + mt * 16 + quad * 4) = ov;
    }
}

extern "C" void kernel_launch(void* const* d_in, const int* in_sizes, int n_in,
                              void* d_out, int out_size, void* d_ws, size_t ws_size,
                              hipStream_t stream) {
    const float* x  = (const float*)d_in[0];
    const float* Wq = (const float*)d_in[1];
    const float* Wk = (const float*)d_in[2];
    const float* Wv = (const float*)d_in[3];
    const float* Wo = (const float*)d_in[4];
    const float* bo = (const float*)d_in[5];
    const float* W1 = (const float*)d_in[6];
    const float* b1 = (const float*)d_in[7];
    const float* W2 = (const float*)d_in[8];
    const float* b2 = (const float*)d_in[9];
    const float* g1 = (const float*)d_in[10];
    const float* g2 = (const float*)d_in[11];
    float* out = (float*)d_out;
    char* ws = (char*)d_ws;

    bf16_t* qkvw_bt = (bf16_t*)(ws);                    // 2304x768
    bf16_t* wo_bt   = (bf16_t*)(ws + 3538944);          // 768x768
    bf16_t* w1_bt   = (bf16_t*)(ws + 4718592);          // 3072x768 (interleaved)
    bf16_t* w2_bt   = (bf16_t*)(ws + 9437184);          // 768x1536
    bf16_t* h_bf    = (bf16_t*)(ws + 11796480);         // 4096x768
    bf16_t* qkv     = (bf16_t*)(ws + 18087936);         // 4096x2304 (Q,K used)
    bf16_t* attn_bf = (bf16_t*)(ws + 36962304);         // 4096x768
    bf16_t* sw_bf   = (bf16_t*)(ws + 68419584);         // 4096x1536
    bf16_t* vt      = (bf16_t*)(ws + 81002496);         // 24x64x2048

    // fused: weight pack (1440 blocks) + rmsnorm #1 (4096 blocks)
    pack_rms<<<5536, 256, 0, stream>>>(Wq, Wk, Wv, Wo, W1, W2,
                                       qkvw_bt, wo_bt, w1_bt, w2_bt,
                                       x, g1, h_bf);

    // qkv = h @ [Wq|Wk|Wv]: Q,K -> qkv buffer; V -> vt (transposed), fused
    gemm_bf16<128, 2><<<576, 256, 0, stream>>>(
        h_bf, qkvw_bt, 768, nullptr, qkv, 2304, nullptr, nullptr, 18, vt);

    attn_mfma<<<768, 256, 0, stream>>>(qkv, vt, attn_bf);

    // out = x + attn @ Wo + bo  (fp32): 6x64 -> 384 blocks
    gemm_bf16<64, 0><<<384, 256, 0, stream>>>(
        attn_bf, wo_bt, 768, out, nullptr, 768, bo, x, 6, nullptr);

    rmsnorm_bf<<<NROWS, 256, 0, stream>>>(out, g2, h_bf);

    // sw = silu(gate) * a, fused into the W1 GEMM epilogue: 24x32 -> 768 blocks
    gemm_bf16<128, 1><<<768, 256, 0, stream>>>(
        h_bf, w1_bt, 768, nullptr, sw_bf, 1536, b1, nullptr, 24, nullptr);

    // out = out + sw @ W2 + b2  (fp32): 6x64 -> 384 blocks
    gemm_bf16<64, 0><<<384, 256, 0, stream>>>(
        sw_bf, w2_bt, 1536, out, nullptr, 768, b2, out, 6, nullptr);
}

// Round 12
// 251.373 us; speedup vs baseline: 1.0820x; 1.0062x over previous
//
#include <hip/hip_runtime.h>
#include <math.h>

// Problem constants: B=2, T=2048, D=768, H=12, HS=64, FF=3072, HALF=1536
#define TDIM 2048
#define DDIM 768
#define NH   12
#define NROWS 4096            // B*T
#define EPSV 1e-8f
#define SCALE 0.03608439182435161f   // 768^-0.5  (ref scales by D, not HS)

typedef __bf16 bf16_t;
typedef bf16_t bf16x8 __attribute__((ext_vector_type(8)));
typedef bf16_t bf16x4 __attribute__((ext_vector_type(4)));
typedef bf16_t bf16x2 __attribute__((ext_vector_type(2)));
typedef float  floatx4 __attribute__((ext_vector_type(4)));

// async global->LDS, 16B per lane; LDS dest = wave-uniform base + lane*16
__device__ __forceinline__ void glds16(const bf16_t* g, bf16_t* l) {
    __builtin_amdgcn_global_load_lds(
        (const __attribute__((address_space(1))) void*)g,
        (__attribute__((address_space(3))) void*)l, 16, 0, 0);
}

// ------- fused: weight repack (blocks 0..1439) + RMSNorm #1 (1440..5535) -----
// pack: 64x64 fp32->bf16 tile transpose. [0,144) Wo, [144,720) W1 (a/g
// column-interleaved for fused SwiGLU), [720,1008) W2, [1008,1440) QKV.
// rmsnorm: row = bid - 1440.
__global__ __launch_bounds__(256) void pack_rms(
    const float* __restrict__ Wq, const float* __restrict__ Wk,
    const float* __restrict__ Wv, const float* __restrict__ Wo,
    const float* __restrict__ W1, const float* __restrict__ W2,
    bf16_t* __restrict__ qkvw, bf16_t* __restrict__ wo,
    bf16_t* __restrict__ w1, bf16_t* __restrict__ w2,
    const float* __restrict__ x, const float* __restrict__ g1,
    bf16_t* __restrict__ hout)
{
    __shared__ float Ts[64][65];
    __shared__ float red[4];
    __shared__ float tot;
    int bid = blockIdx.x;
    int tid = threadIdx.x;

    if (bid >= 1440) {                     // ---- RMSNorm path ----
        int row = bid - 1440;
        const float* xr = x + (size_t)row * DDIM;
        float v0 = xr[tid], v1 = xr[tid + 256], v2 = xr[tid + 512];
        float s = v0*v0 + v1*v1 + v2*v2;
        #pragma unroll
        for (int off = 32; off > 0; off >>= 1)
            s += __shfl_down(s, off, 64);
        if ((tid & 63) == 0) red[tid >> 6] = s;
        __syncthreads();
        if (tid == 0) tot = red[0] + red[1] + red[2] + red[3];
        __syncthreads();
        float rms = sqrtf(tot * (1.0f / DDIM));
        float inv = 1.0f / (rms + EPSV);
        bf16_t* orow = hout + (size_t)row * DDIM;
        orow[tid]       = (bf16_t)(g1[tid]       * v0 * inv);
        orow[tid + 256] = (bf16_t)(g1[tid + 256] * v1 * inv);
        orow[tid + 512] = (bf16_t)(g1[tid + 512] * v2 * inv);
        return;
    }

    // ---- pack path ----
    const float* src; bf16_t* dst;
    int srcld, dstld, k0, n0;
    int remap = 0;
    if (bid < 144) {                       // Wo: K=768, N=768 (12x12)
        int kx = bid % 12, nx = bid / 12;
        src = Wo; dst = wo; srcld = 768; dstld = 768; k0 = kx * 64; n0 = nx * 64;
    } else if (bid < 720) {                // W1: K=768, N=3072 (12x48)
        int t = bid - 144; int kx = t % 12, nx = t / 12;
        src = W1; dst = w1; srcld = 3072; dstld = 768; k0 = kx * 64; n0 = nx * 64;
        remap = 1;                         // interleave a/gate columns
    } else if (bid < 1008) {               // W2: K=1536, N=768 (24x12)
        int t = bid - 720; int kx = t % 24, nx = t / 24;
        src = W2; dst = w2; srcld = 768; dstld = 1536; k0 = kx * 64; n0 = nx * 64;
    } else {                               // QKV: 36 mats (768x64), 12 k-tiles
        int t = bid - 1008; int kx = t % 12, y = t / 12;
        int sel = y / 12, h = y - sel * 12;
        src = ((sel == 0) ? Wq : (sel == 1) ? Wk : Wv) + (size_t)h * 768 * 64;
        dst = qkvw + (size_t)(sel * 768 + h * 64) * 768;
        srcld = 64; dstld = 768; k0 = kx * 64; n0 = 0;
    }
    int r = tid >> 2, c = (tid & 3) * 16;
    const float* s = src + (size_t)(k0 + r) * srcld + n0 + c;
    #pragma unroll
    for (int i = 0; i < 4; i++) {
        float4 t = *(const float4*)(s + i * 4);
        Ts[r][c + i*4 + 0] = t.x; Ts[r][c + i*4 + 1] = t.y;
        Ts[r][c + i*4 + 2] = t.z; Ts[r][c + i*4 + 3] = t.w;
    }
    __syncthreads();
    int n = tid >> 2, kk = (tid & 3) * 16;
    bf16x8 o0, o1;
    #pragma unroll
    for (int i = 0; i < 8; i++) {
        o0[i] = (bf16_t)Ts[kk + i][n];
        o1[i] = (bf16_t)Ts[kk + 8 + i][n];
    }
    int oc = n0 + n;
    if (remap) oc = (oc < 1536) ? (oc * 2) : ((oc - 1536) * 2 + 1);
    bf16_t* d = dst + (size_t)oc * dstld + k0 + kk;
    *(bf16x8*)d = o0;
    *(bf16x8*)(d + 8) = o1;
}

// ---------------- RMSNorm -> bf16 (second norm) ----------------
__global__ __launch_bounds__(256) void rmsnorm_bf(
    const float* __restrict__ x, const float* __restrict__ g,
    bf16_t* __restrict__ out)
{
    int row = blockIdx.x;
    int tid = threadIdx.x;
    const float* xr = x + (size_t)row * DDIM;
    float v0 = xr[tid], v1 = xr[tid + 256], v2 = xr[tid + 512];
    float s = v0*v0 + v1*v1 + v2*v2;
    #pragma unroll
    for (int off = 32; off > 0; off >>= 1)
        s += __shfl_down(s, off, 64);
    __shared__ float red[4];
    __shared__ float tot;
    if ((tid & 63) == 0) red[tid >> 6] = s;
    __syncthreads();
    if (tid == 0) tot = red[0] + red[1] + red[2] + red[3];
    __syncthreads();
    float rms = sqrtf(tot * (1.0f / DDIM));
    float inv = 1.0f / (rms + EPSV);
    bf16_t* orow = out + (size_t)row * DDIM;
    orow[tid]       = (bf16_t)(g[tid]       * v0 * inv);
    orow[tid + 256] = (bf16_t)(g[tid + 256] * v1 * inv);
    orow[tid + 512] = (bf16_t)(g[tid + 512] * v2 * inv);
}

// ---------------- bf16 MFMA GEMM, BK=64 twin-buffer, C^T epilogue ------------
// R6-exact K-loop (measured best). C[M x N] = A[M x K] * BT[N x K]^T.
// Tile TM x 128, 4 waves 2x2 per k-half. 1-D grid + XCD swizzle (T1).
// Explicit pipelining REGRESSED 30% (R7, m141) — do not reintroduce.
// KS=2 (in-block split-K, 512 threads): waves 0-3 take K-half 0, waves 4-7
// K-half 1 with private LDS staging; each barrier period covers 2 K-steps
// (drain amortization x2 at 1.5 blocks/CU where no inter-block overlap
// exists) and waves/CU double. Halves combine via LDS (stride-33, conflict-
// free, overlays dead staging buffers), half-0 runs the epilogue. Determin-
// istic, no atomics.
// EPI=0: bias/resid, fp32/bf16 out. EPI=1: fused SwiGLU (a/g interleaved BT).
// EPI=2 (qkv): cols <1536 -> qkv buffer; V cols -> vt[bh][d][t] transposed.
template<int TM, int EPI, int KS>
__global__ __launch_bounds__(KS * 256) void gemm_bf16(
    const bf16_t* __restrict__ A, const bf16_t* __restrict__ BT, int K,
    float* __restrict__ Cf, bf16_t* __restrict__ Cb, int ldc,
    const float* __restrict__ bias, const float* __restrict__ resid, int gx,
    bf16_t* __restrict__ vtout)
{
    constexpr int MT = TM / 32;           // m-frags per wave (4 or 2)
    constexpr int HB = TM * 128 + 16384;  // staging bytes per k-half
    __shared__ char lraw[KS * HB];
    int tid = threadIdx.x;
    int kh = tid >> 8;                    // k-half (always 0 for KS=1)
    int t2 = tid & 255;
    char* hb = lraw + kh * HB;
    auto As0 = (bf16_t(*)[32])(hb);
    auto As1 = (bf16_t(*)[32])(hb + TM * 64);
    auto Bs0 = (bf16_t(*)[32])(hb + TM * 128);
    auto Bs1 = (bf16_t(*)[32])(hb + TM * 128 + 8192);
    int wave = t2 >> 6, lane = t2 & 63;
    int lrow = lane & 15, quad = lane >> 4;
    int wm = wave >> 1, wn = wave & 1;

    // XCD swizzle: nwg % 8 == 0 for all launches
    int flat = blockIdx.x;
    int cpx = gridDim.x >> 3;
    int swz = (flat & 7) * cpx + (flat >> 3);
    int m0 = (swz / gx) * TM;
    int n0 = (swz % gx) * 128;

    int K2 = K / KS;
    int srow = lane >> 2, scol = (lane & 3) * 8;     // 16 rows x 8 elems per glds
    const bf16_t* Ag = A  + ((size_t)m0 + wave * (TM/4) + srow) * K + kh * K2 + scol;
    const bf16_t* Bg = BT + ((size_t)n0 + wave * 32 + srow) * K + kh * K2 + scol;

    floatx4 acc[MT][4];
    #pragma unroll
    for (int mt = 0; mt < MT; mt++)
        #pragma unroll
        for (int nt = 0; nt < 4; nt++)
            #pragma unroll
            for (int r = 0; r < 4; r++) acc[mt][nt][r] = 0.f;

    for (int k0 = 0; k0 < K2; k0 += 64) {
        __syncthreads();
        #pragma unroll
        for (int i = 0; i < TM/64; i++) {            // 2 (TM=128) or 1 (TM=64)
            glds16(Ag + (size_t)(i*16) * K + k0,      &As0[wave*(TM/4) + i*16][0]);
            glds16(Ag + (size_t)(i*16) * K + k0 + 32, &As1[wave*(TM/4) + i*16][0]);
        }
        #pragma unroll
        for (int i = 0; i < 2; i++) {
            glds16(Bg + (size_t)(i*16) * K + k0,      &Bs0[wave*32 + i*16][0]);
            glds16(Bg + (size_t)(i*16) * K + k0 + 32, &Bs1[wave*32 + i*16][0]);
        }
        __syncthreads();

        bf16x8 af0[MT], af1[MT], bf0[4], bf1[4];
        #pragma unroll
        for (int mt = 0; mt < MT; mt++) {
            af0[mt] = *(const bf16x8*)&As0[wm*(TM/2) + mt*16 + lrow][quad * 8];
            af1[mt] = *(const bf16x8*)&As1[wm*(TM/2) + mt*16 + lrow][quad * 8];
        }
        #pragma unroll
        for (int nt = 0; nt < 4; nt++) {
            bf0[nt] = *(const bf16x8*)&Bs0[wn*64 + nt*16 + lrow][quad * 8];
            bf1[nt] = *(const bf16x8*)&Bs1[wn*64 + nt*16 + lrow][quad * 8];
        }
        #pragma unroll
        for (int mt = 0; mt < MT; mt++)
            #pragma unroll
            for (int nt = 0; nt < 4; nt++) {
                acc[mt][nt] = __builtin_amdgcn_mfma_f32_16x16x32_bf16(
                    bf0[nt], af0[mt], acc[mt][nt], 0, 0, 0);
                acc[mt][nt] = __builtin_amdgcn_mfma_f32_16x16x32_bf16(
                    bf1[nt], af1[mt], acc[mt][nt], 0, 0, 0);
            }
    }

    if constexpr (KS == 2) {
        // combine halves: half-1 parks partials in LDS (stride 33 dwords ->
        // (lane+j)%32 banks, conflict-free), half-0 adds. Overlays staging.
        __syncthreads();                   // last k-step's LDS reads complete
        float* comb = (float*)lraw;
        float* p = comb + (size_t)(wave * 64 + lane) * 33;
        if (kh == 1) {
            #pragma unroll
            for (int mt = 0; mt < MT; mt++)
                #pragma unroll
                for (int nt = 0; nt < 4; nt++)
                    #pragma unroll
                    for (int r = 0; r < 4; r++)
                        p[mt*16 + nt*4 + r] = acc[mt][nt][r];
        }
        __syncthreads();
        if (kh == 1) return;
        #pragma unroll
        for (int mt = 0; mt < MT; mt++)
            #pragma unroll
            for (int nt = 0; nt < 4; nt++)
                #pragma unroll
                for (int r = 0; r < 4; r++)
                    acc[mt][nt][r] += p[mt*16 + nt*4 + r];
    }

    // epilogue (C^T layout): row = m0+wm*(TM/2)+mt*16+lrow,
    //                        col = n0+wn*64+nt*16+quad*4 .. +4
    int crow0 = m0 + wm * (TM/2);
    int ccol0 = n0 + wn * 64;
    #pragma unroll
    for (int mt = 0; mt < MT; mt++) {
        int row = crow0 + mt * 16 + lrow;
        #pragma unroll
        for (int nt = 0; nt < 4; nt++) {
            int col = ccol0 + nt * 16 + quad * 4;
            floatx4 a = acc[mt][nt];
            if constexpr (EPI == 1) {
                // cols = {a_c, g_c, a_{c+1}, g_{c+1}}, c = col/2
                int c = col >> 1;
                float2 ba = *(const float2*)(bias + c);
                float2 bg = *(const float2*)(bias + 1536 + c);
                float a0 = a[0] + ba.x, g0 = a[1] + bg.x;
                float a1 = a[2] + ba.y, g1 = a[3] + bg.y;
                bf16x2 v;
                v[0] = (bf16_t)(a0 * (g0 / (1.0f + __expf(-g0))));
                v[1] = (bf16_t)(a1 * (g1 / (1.0f + __expf(-g1))));
                *(bf16x2*)(Cb + (size_t)row * ldc + c) = v;
            } else if constexpr (EPI == 2) {
                if (col < 1536) {              // Q/K part -> qkv buffer
                    bf16x4 v;
                    v[0] = (bf16_t)a[0]; v[1] = (bf16_t)a[1];
                    v[2] = (bf16_t)a[2]; v[3] = (bf16_t)a[3];
                    *(bf16x4*)(Cb + (size_t)row * ldc + col) = v;
                } else {                       // V part -> vt[bh][d][t]
                    int vcol = col - 1536;
                    int hh = vcol >> 6, d0 = vcol & 63;
                    int bb = row >> 11, tt = row & 2047;
                    bf16_t* vbase2 = vtout +
                        ((size_t)(bb * NH + hh) * 64 + d0) * TDIM + tt;
                    #pragma unroll
                    for (int r = 0; r < 4; r++)
                        vbase2[(size_t)r * TDIM] = (bf16_t)a[r];
                }
            } else {
                size_t off = (size_t)row * ldc + col;
                float4 bv = make_float4(0.f, 0.f, 0.f, 0.f);
                if (bias) bv = *(const float4*)(bias + col);
                float4 rs = make_float4(0.f, 0.f, 0.f, 0.f);
                if (resid) rs = *(const float4*)(resid + off);
                if (Cf) {
                    float4 v;
                    v.x = a[0] + bv.x + rs.x; v.y = a[1] + bv.y + rs.y;
                    v.z = a[2] + bv.z + rs.z; v.w = a[3] + bv.w + rs.w;
                    *(float4*)(Cf + off) = v;
                } else {
                    bf16x4 v;
                    v[0] = (bf16_t)(a[0] + bv.x + rs.x);
                    v[1] = (bf16_t)(a[1] + bv.y + rs.y);
                    v[2] = (bf16_t)(a[2] + bv.z + rs.z);
                    v[3] = (bf16_t)(a[3] + bv.w + rs.w);
                    *(bf16x4*)(Cb + off) = v;
                }
            }
        }
    }
}

// ---------------- MFMA flash attention, S^T formulation ----------------
// v3 (parked — best measured attn variant, 44.8us). Balanced CU schedule:
// blocks {c, c+256, c+512} land on the same CU; qt triples sum to 46/47.
// Double-buffered K/V, reg-prefetch 2 tiles ahead, mid-loop write-late staging,
// lgkmcnt-only barrier, setprio on MFMA clusters, deferred rescale (THR=8).
// SIX structural variants (R0-R9) land 44.8-61us; v3 is the floor. The cost
// is the intrinsic per-iteration dependency chain (QK->softmax->PV->barrier),
// not any single pipe: v6 zeroed bank conflicts and cut FETCH 3x yet ran 35%
// slower (fewer blocks, heavier per-iter body). Keep v3.
__global__ __launch_bounds__(256) void attn_mfma(
    const bf16_t* __restrict__ qkv, const bf16_t* __restrict__ vt,
    bf16_t* __restrict__ o)
{
    const int QS = 2304;
    int bid = blockIdx.x;
    int c = bid & 255, slot = bid >> 8;
    int x = c & 31, g = c >> 5;
    int qt, bh;
    if (slot == 0)      { bh = g;      qt = x; }
    else if (slot == 1) { bh = 8 + g;  qt = (x + 16) & 31; }
    else                { bh = 16 + g; qt = (x < 16) ? (31 - 2 * x) : (62 - 2 * x); }
    int b = bh / NH, h = bh - b * NH;
    int tid = threadIdx.x;
    int wave = tid >> 6, lane = tid & 63;
    int lrow = lane & 15, quad = lane >> 4;

    __shared__ bf16_t Ks[2][64][72];      // K tile: row = kcol, col = dim
    __shared__ bf16_t Vts[2][64][72];     // V^T: row = dim, col = kcol
    __shared__ bf16_t Ps[4][16][72];      // per-wave P (row = q, col = kc)

    size_t rbase = (size_t)b * TDIM;
    int q0 = qt * 64, qrow_w = q0 + wave * 16;

    const bf16_t* qp = qkv + (rbase + qrow_w + lrow) * QS + h * 64;
    bf16x8 qf[2];
    qf[0] = *(const bf16x8*)(qp + quad * 8);
    qf[1] = *(const bf16x8*)(qp + 32 + quad * 8);

    floatx4 o_acc[4];   // O^T: (dim = mt*16 + quad*4 + r, q = lrow)
    #pragma unroll
    for (int mt = 0; mt < 4; mt++)
        #pragma unroll
        for (int r = 0; r < 4; r++) o_acc[mt][r] = 0.f;
    float m_r = -INFINITY, l_r = 0.f;

    int srow = tid >> 2;            // 0..63
    int scol = (tid & 3) * 16;      // 0,16,32,48
    const bf16_t* kbase = qkv + (rbase + srow) * QS + 768 + h * 64 + scol;
    const bf16_t* vbase = vt + ((size_t)bh * 64 + srow) * TDIM + scol;

    // prologue: tile 0 -> LDS buf0; issue prefetch of tile 1 into regs
    bf16x8 kr0 = *(const bf16x8*)kbase;
    bf16x8 kr1 = *(const bf16x8*)(kbase + 8);
    bf16x8 vr0 = *(const bf16x8*)vbase;
    bf16x8 vr1 = *(const bf16x8*)(vbase + 8);
    *(bf16x8*)&Ks[0][srow][scol]      = kr0;
    *(bf16x8*)&Ks[0][srow][scol + 8]  = kr1;
    *(bf16x8*)&Vts[0][srow][scol]     = vr0;
    *(bf16x8*)&Vts[0][srow][scol + 8] = vr1;
    if (qt >= 1) {
        const bf16_t* kp = kbase + (size_t)64 * QS;
        const bf16_t* vp = vbase + 64;
        kr0 = *(const bf16x8*)kp;  kr1 = *(const bf16x8*)(kp + 8);
        vr0 = *(const bf16x8*)vp;  vr1 = *(const bf16x8*)(vp + 8);
    }
    asm volatile("s_waitcnt lgkmcnt(0)" ::: "memory");
    __builtin_amdgcn_s_barrier();

    for (int s = 0; s <= qt; s++) {
        int cur = s & 1;

        // S^T = K Q^T : C row = kc (nt*16 + quad*4 + r), col = q (lrow)
        floatx4 sfrag[4];
        __builtin_amdgcn_s_setprio(1);
        #pragma unroll
        for (int nt = 0; nt < 4; nt++) {
            floatx4 a;
            #pragma unroll
            for (int r = 0; r < 4; r++) a[r] = 0.f;
            #pragma unroll
            for (int kf = 0; kf < 2; kf++) {
                bf16x8 afr = *(const bf16x8*)&Ks[cur][nt * 16 + lrow][kf * 32 + quad * 8];
                a = __builtin_amdgcn_mfma_f32_16x16x32_bf16(afr, qf[kf], a, 0, 0, 0);
            }
            sfrag[nt] = a;
        }
        __builtin_amdgcn_s_setprio(0);

        // write-late: stage tile s+1 (regs loaded an iteration ago) into the
        // idle buffer — other waves are only reading buf[cur], no barrier needed
        if (s < qt) {
            int nxt = cur ^ 1;
            *(bf16x8*)&Ks[nxt][srow][scol]      = kr0;
            *(bf16x8*)&Ks[nxt][srow][scol + 8]  = kr1;
            *(bf16x8*)&Vts[nxt][srow][scol]     = vr0;
            *(bf16x8*)&Vts[nxt][srow][scol + 8] = vr1;
        }

        if (s == qt) {
            int qg = qrow_w + lrow;
            #pragma unroll
            for (int nt = 0; nt < 4; nt++)
                #pragma unroll
                for (int r = 0; r < 4; r++) {
                    int kc = s * 64 + nt * 16 + quad * 4 + r;
                    sfrag[nt][r] = (kc > qg) ? -INFINITY : sfrag[nt][r] * SCALE;
                }
        } else {
            #pragma unroll
            for (int nt = 0; nt < 4; nt++)
                #pragma unroll
                for (int r = 0; r < 4; r++) sfrag[nt][r] *= SCALE;
        }

        // online softmax over kc: reg-max + 2 shfls, deferred rescale (THR=8)
        float mx = sfrag[0][0];
        #pragma unroll
        for (int nt = 0; nt < 4; nt++)
            #pragma unroll
            for (int r = 0; r < 4; r++) mx = fmaxf(mx, sfrag[nt][r]);
        mx = fmaxf(mx, __shfl_xor(mx, 16, 64));
        mx = fmaxf(mx, __shfl_xor(mx, 32, 64));
        if (__any(mx > m_r + 8.0f)) {
            float mn = fmaxf(m_r, mx);
            float alpha = __expf(m_r - mn);
            m_r = mn;
            l_r *= alpha;
            #pragma unroll
            for (int mt = 0; mt < 4; mt++)
                #pragma unroll
                for (int r = 0; r < 4; r++) o_acc[mt][r] *= alpha;
        }

        float ls = 0.f;
        #pragma unroll
        for (int nt = 0; nt < 4; nt++) {
            bf16x4 pv;
            #pragma unroll
            for (int r = 0; r < 4; r++) {
                float p = __expf(sfrag[nt][r] - m_r);
                ls += p;
                pv[r] = (bf16_t)p;
            }
            *(bf16x4*)&Ps[wave][lrow][nt * 16 + quad * 4] = pv;
        }
        ls += __shfl_xor(ls, 16, 64);
        ls += __shfl_xor(ls, 32, 64);
        l_r += ls;

        // O^T += V^T P^T (wave-private Ps: no barrier needed)
        __builtin_amdgcn_s_setprio(1);
        #pragma unroll
        for (int kf = 0; kf < 2; kf++) {
            bf16x8 pfr = *(const bf16x8*)&Ps[wave][lrow][kf * 32 + quad * 8];
            #pragma unroll
            for (int mt = 0; mt < 4; mt++) {
                bf16x8 vfr = *(const bf16x8*)&Vts[cur][mt * 16 + lrow][kf * 32 + quad * 8];
                o_acc[mt] = __builtin_amdgcn_mfma_f32_16x16x32_bf16(vfr, pfr, o_acc[mt], 0, 0, 0);
            }
        }
        __builtin_amdgcn_s_setprio(0);

        // issue-early: global loads for tile s+2 (consumed next iteration)
        if (s + 2 <= qt) {
            const bf16_t* kp = kbase + (size_t)(s + 2) * 64 * QS;
            const bf16_t* vp = vbase + (size_t)(s + 2) * 64;
            kr0 = *(const bf16x8*)kp;  kr1 = *(const bf16x8*)(kp + 8);
            vr0 = *(const bf16x8*)vp;  vr1 = *(const bf16x8*)(vp + 8);
        }

        // LDS-only fence + raw barrier: keep the global prefetch in flight
        asm volatile("s_waitcnt lgkmcnt(0)" ::: "memory");
        __builtin_amdgcn_s_barrier();
    }

    float inv = 1.0f / l_r;
    size_t rb = (rbase + qrow_w + lrow) * DDIM + h * 64;
    #pragma unroll
    for (int mt = 0; mt < 4; mt++) {
        bf16x4 ov;
        #pragma unroll
        for (int r = 0; r < 4; r++) ov[r] = (bf16_t)(o_acc[mt][r] * inv);
        *(bf16x4*)(o + rb + mt * 16 + quad * 4) = ov;
    }
}

extern "C" void kernel_launch(void* const* d_in, const int* in_sizes, int n_in,
                              void* d_out, int out_size, void* d_ws, size_t ws_size,
                              hipStream_t stream) {
    const float* x  = (const float*)d_in[0];
    const float* Wq = (const float*)d_in[1];
    const float* Wk = (const float*)d_in[2];
    const float* Wv = (const float*)d_in[3];
    const float* Wo = (const float*)d_in[4];
    const float* bo = (const float*)d_in[5];
    const float* W1 = (const float*)d_in[6];
    const float* b1 = (const float*)d_in[7];
    const float* W2 = (const float*)d_in[8];
    const float* b2 = (const float*)d_in[9];
    const float* g1 = (const float*)d_in[10];
    const float* g2 = (const float*)d_in[11];
    float* out = (float*)d_out;
    char* ws = (char*)d_ws;

    bf16_t* qkvw_bt = (bf16_t*)(ws);                    // 2304x768
    bf16_t* wo_bt   = (bf16_t*)(ws + 3538944);          // 768x768
    bf16_t* w1_bt   = (bf16_t*)(ws + 4718592);          // 3072x768 (interleaved)
    bf16_t* w2_bt   = (bf16_t*)(ws + 9437184);          // 768x1536
    bf16_t* h_bf    = (bf16_t*)(ws + 11796480);         // 4096x768
    bf16_t* qkv     = (bf16_t*)(ws + 18087936);         // 4096x2304 (Q,K used)
    bf16_t* attn_bf = (bf16_t*)(ws + 36962304);         // 4096x768
    bf16_t* sw_bf   = (bf16_t*)(ws + 68419584);         // 4096x1536
    bf16_t* vt      = (bf16_t*)(ws + 81002496);         // 24x64x2048

    // fused: weight pack (1440 blocks) + rmsnorm #1 (4096 blocks)
    pack_rms<<<5536, 256, 0, stream>>>(Wq, Wk, Wv, Wo, W1, W2,
                                       qkvw_bt, wo_bt, w1_bt, w2_bt,
                                       x, g1, h_bf);

    // qkv = h @ [Wq|Wk|Wv]: Q,K -> qkv buffer; V -> vt (transposed), fused
    gemm_bf16<128, 2, 1><<<576, 256, 0, stream>>>(
        h_bf, qkvw_bt, 768, nullptr, qkv, 2304, nullptr, nullptr, 18, vt);

    attn_mfma<<<768, 256, 0, stream>>>(qkv, vt, attn_bf);

    // out = x + attn @ Wo + bo  (fp32): split-K=2, 384 blocks x 512 thr
    gemm_bf16<64, 0, 2><<<384, 512, 0, stream>>>(
        attn_bf, wo_bt, 768, out, nullptr, 768, bo, x, 6, nullptr);

    rmsnorm_bf<<<NROWS, 256, 0, stream>>>(out, g2, h_bf);

    // sw = silu(gate) * a, fused into the W1 GEMM epilogue: 768 blocks
    gemm_bf16<128, 1, 1><<<768, 256, 0, stream>>>(
        h_bf, w1_bt, 768, nullptr, sw_bf, 1536, b1, nullptr, 24, nullptr);

    // out = out + sw @ W2 + b2  (fp32): split-K=2, 384 blocks x 512 thr
    gemm_bf16<64, 0, 2><<<384, 512, 0, stream>>>(
        sw_bf, w2_bt, 1536, out, nullptr, 768, b2, out, 6, nullptr);
}